// Round 5
// baseline (520.887 us; speedup 1.0000x reference)
//
#include <hip/hip_runtime.h>
#include <cstdint>

// ============================================================================
// QunatEncoderBlock: windowed attention block with int8 fake-quant.
// All qlinear / QK^T / PV matmuls are EXACT in int8xint8->int32 (MFMA i8).
// Rel-pos bias via bf16 MFMA with hi/lo split tables (error ~2^-18).
// R1: k_attn 1-wave/1-tile blocks (grid 13x1200, 64 thr): 152us -> ~60us.
// R2: branch-free erf gelu: lin1 99->89us.
// R3: chunk-XOR LDS swizzle (conflicts 4.7M->0) + depth-2 vmcnt pipeline:
//     time-null but kept (known-good 478us baseline).
// R4: 8-phase 256^2 port REGRESSED (1 block/CU, short-K pipeline, serialized
//     epilogue rounds) -> reverted; k_gemm below is the R3 version.
// R5: k_attn swapped-QK^T register-resident P: mfma(K,Q) puts a full P-row
//     in each lane (q = lane&15); softmax reduce = in-lane + 2 shfl_xor;
//     P quantized to words and moved to PV A-frags by an in-register 4x4
//     quad-word transpose (32 shfl_xor). Eliminates 208 ds_write_b8 +
//     16 ds_read_b128 per wave (LDS-issue-bound kernel: ~392 -> ~156 ops).
//     + k_prep: 4x wquant + relpack fused into one launch (11 -> 8).
// ============================================================================

typedef int   v4i __attribute__((ext_vector_type(4)));
typedef float v4f __attribute__((ext_vector_type(4)));
typedef short v8s __attribute__((ext_vector_type(8)));
typedef int8_t i8;

__device__ __forceinline__ i8 satq(float x) {   // x already scale-divided
  float q = rintf(x);
  q = fminf(127.f, fmaxf(-128.f, q));
  return (i8)(int)q;
}

__device__ __forceinline__ void gload16(const i8* g, i8* l) {
  __builtin_amdgcn_global_load_lds((const __attribute__((address_space(1))) void*)g,
                                   (__attribute__((address_space(3))) void*)l, 16, 0, 0);
}

__device__ __forceinline__ int pack4(const i8* q) {
  return ((int)(unsigned char)q[0]) | ((int)(unsigned char)q[1] << 8) |
         ((int)(unsigned char)q[2] << 16) | ((int)(unsigned char)q[3] << 24);
}

// branch-free gelu: 0.5*v*(1+erf(v/sqrt2)), erf via A-S 7.1.26 (|err|<=1.5e-7)
__device__ __forceinline__ float fast_gelu(float v) {
  float x = fabsf(v) * 0.70710678118654752f;
  float t = __builtin_amdgcn_rcpf(fmaf(0.3275911f, x, 1.0f));
  float s = fmaf(1.061405429f, t, -1.453152027f);
  s = fmaf(s, t, 1.421413741f);
  s = fmaf(s, t, -0.284496736f);
  s = fmaf(s, t, 0.254829592f);
  s = s * t;
  float e = __expf(-x * x);
  float erfa = fmaf(-s, e, 1.0f);          // erf(|x|)
  float erfs = copysignf(erfa, v);
  float hv = 0.5f * v;
  return fmaf(hv, erfs, hv);
}

// ---------------------------------------------------------------------------
// k_prep: all 4 weight fake-quants (outputs are contiguous in wqb, region
// boundaries 256-aligned -> block-uniform) + rel-pos table pack, one launch.
// blocks [0,1728): wquant; blocks [1728,1732): relpack.
// ---------------------------------------------------------------------------
__global__ __launch_bounds__(256) void k_prep(const float* __restrict__ qkvw,
    const float* __restrict__ projw, const float* __restrict__ lin1w,
    const float* __restrict__ lin2w, i8* __restrict__ wqb,
    const float* __restrict__ rph, const float* __restrict__ rpw,
    short* __restrict__ TB, const float* __restrict__ wsc) {
  int b = blockIdx.x;
  if (b < 1728) {
    int i = b * 256 + threadIdx.x;          // < 442368
    const float* w; int base, sidx;
    if (i < 110592)      { w = qkvw;  base = 0;      sidx = 0; }
    else if (i < 147456) { w = projw; base = 110592; sidx = 1; }
    else if (i < 294912) { w = lin1w; base = 147456; sidx = 2; }
    else                 { w = lin2w; base = 294912; sidx = 3; }
    float inv = 1.0f / wsc[sidx];
    const float4* src = (const float4*)w + (size_t)(i - base) * 4;
    i8 buf[16];
#pragma unroll
    for (int t = 0; t < 4; t++) {
      float4 f = src[t];
      buf[t*4+0] = satq(f.x * inv); buf[t*4+1] = satq(f.y * inv);
      buf[t*4+2] = satq(f.z * inv); buf[t*4+3] = satq(f.w * inv);
    }
    *(v4i*)(wqb + (size_t)i * 16) = *(v4i*)buf;
  } else {
    // rel-pos pack: chunk c = (tb*2+nt)*4 + ks*2 + p; frag = TB[c*512+lane*8..]
    // B[n][k] = table[n*64+k] (n<27 else 0), n = nt*16+(lane&15),
    // k = ks*32+(lane>>4)*8+j
    int g = (b - 1728) * 256 + threadIdx.x;  // < 1024
    int lane = g & 63, c = g >> 6;
    int p = c & 1, ks = (c >> 1) & 1, nt = (c >> 2) & 1, tb = c >> 3;
    const float* src = tb ? rpw : rph;
    int n = nt * 16 + (lane & 15);
    int k0 = ks * 32 + (lane >> 4) * 8;
    short outv[8];
#pragma unroll
    for (int j = 0; j < 8; j++) {
      float v = (n < 27) ? src[n * 64 + k0 + j] : 0.f;
      unsigned u = __float_as_uint(v);
      unsigned hi = (u + 0x7fffu + ((u >> 16) & 1u)) >> 16;
      if (p == 0) outv[j] = (short)hi;
      else {
        float lof = v - __uint_as_float(hi << 16);
        unsigned ul = __float_as_uint(lof);
        outv[j] = (short)((ul + 0x7fffu + ((ul >> 16) & 1u)) >> 16);
      }
    }
    *(v8s*)(TB + (size_t)c * 512 + lane * 8) = *(v8s*)outv;
  }
}

// ---------------------------------------------------------------------------
// LN1: wave per window-token (pad 64->70, 5x5 windows of 14x14), quant a_s[4]
// ---------------------------------------------------------------------------
__global__ __launch_bounds__(256) void k_ln1(const float* __restrict__ x,
    const float* __restrict__ w, const float* __restrict__ b,
    const float* __restrict__ as, i8* __restrict__ outq) {
  int wt = blockIdx.x * 4 + (threadIdx.x >> 6);
  int lane = threadIdx.x & 63;
  int win = wt / 196, tok = wt - win * 196;
  int bb = win / 25, wrem = win - bb * 25, wh = wrem / 5, ww = wrem - wh * 5;
  int r = tok / 14, c = tok - r * 14;
  int y = wh * 14 + r, xx = ww * 14 + c;
  i8* dst = outq + (size_t)wt * 768 + lane * 12;
  if (y >= 64 || xx >= 64) {
    ((int*)dst)[0] = 0; ((int*)dst)[1] = 0; ((int*)dst)[2] = 0;
    return;
  }
  const float* row = x + (((size_t)bb * 64 + y) * 64 + xx) * 768 + lane * 12;
  float v[12];
  *(float4*)(v)     = *(const float4*)(row);
  *(float4*)(v + 4) = *(const float4*)(row + 4);
  *(float4*)(v + 8) = *(const float4*)(row + 8);
  float s = 0.f, ss = 0.f;
#pragma unroll
  for (int j = 0; j < 12; j++) { s += v[j]; ss += v[j] * v[j]; }
#pragma unroll
  for (int off = 1; off < 64; off <<= 1) { s += __shfl_xor(s, off); ss += __shfl_xor(ss, off); }
  float mu = s * (1.0f / 768.0f);
  float var = ss * (1.0f / 768.0f) - mu * mu;
  float rstd = 1.0f / sqrtf(var + 1e-6f);
  float inv = 1.0f / as[4];
  float wv[12], bv[12];
  *(float4*)(wv)     = *(const float4*)(w + lane * 12);
  *(float4*)(wv + 4) = *(const float4*)(w + lane * 12 + 4);
  *(float4*)(wv + 8) = *(const float4*)(w + lane * 12 + 8);
  *(float4*)(bv)     = *(const float4*)(b + lane * 12);
  *(float4*)(bv + 4) = *(const float4*)(b + lane * 12 + 4);
  *(float4*)(bv + 8) = *(const float4*)(b + lane * 12 + 8);
  i8 q[12];
#pragma unroll
  for (int j = 0; j < 12; j++) q[j] = satq(((v[j] - mu) * rstd * wv[j] + bv[j]) * inv);
  ((int*)dst)[0] = pack4(q); ((int*)dst)[1] = pack4(q + 4); ((int*)dst)[2] = pack4(q + 8);
}

// ---------------------------------------------------------------------------
// LN2: wave per token, quant a_s[6]
// ---------------------------------------------------------------------------
__global__ __launch_bounds__(256) void k_ln2(const float* __restrict__ x2,
    const float* __restrict__ w, const float* __restrict__ b,
    const float* __restrict__ as, i8* __restrict__ outq) {
  int tokg = blockIdx.x * 4 + (threadIdx.x >> 6);
  int lane = threadIdx.x & 63;
  const float* row = x2 + (size_t)tokg * 768 + lane * 12;
  float v[12];
  *(float4*)(v)     = *(const float4*)(row);
  *(float4*)(v + 4) = *(const float4*)(row + 4);
  *(float4*)(v + 8) = *(const float4*)(row + 8);
  float s = 0.f, ss = 0.f;
#pragma unroll
  for (int j = 0; j < 12; j++) { s += v[j]; ss += v[j] * v[j]; }
#pragma unroll
  for (int off = 1; off < 64; off <<= 1) { s += __shfl_xor(s, off); ss += __shfl_xor(ss, off); }
  float mu = s * (1.0f / 768.0f);
  float var = ss * (1.0f / 768.0f) - mu * mu;
  float rstd = 1.0f / sqrtf(var + 1e-6f);
  float inv = 1.0f / as[6];
  float wv[12], bv[12];
  *(float4*)(wv)     = *(const float4*)(w + lane * 12);
  *(float4*)(wv + 4) = *(const float4*)(w + lane * 12 + 4);
  *(float4*)(wv + 8) = *(const float4*)(w + lane * 12 + 8);
  *(float4*)(bv)     = *(const float4*)(b + lane * 12);
  *(float4*)(bv + 4) = *(const float4*)(b + lane * 12 + 4);
  *(float4*)(bv + 8) = *(const float4*)(b + lane * 12 + 8);
  i8* dst = outq + (size_t)tokg * 768 + lane * 12;
  i8 q[12];
#pragma unroll
  for (int j = 0; j < 12; j++) q[j] = satq(((v[j] - mu) * rstd * wv[j] + bv[j]) * inv);
  ((int*)dst)[0] = pack4(q); ((int*)dst)[1] = pack4(q + 4); ((int*)dst)[2] = pack4(q + 8);
}

// ---------------------------------------------------------------------------
// int8 GEMM: C[M,N] = A[M,K] x B[N,K]^T, 128x128 tile, BK=64.  [R3 version]
// depth-2 pipeline, 3 LDS buffers, counted vmcnt, raw barriers,
// chunk-XOR swizzle, operand-swapped MFMA. N%128==0, K%64==0, K>=128.
// Epi::store4(a, m, n0): a[r] = C[m][n0+r], n0%4==0, m<M guaranteed.
// ---------------------------------------------------------------------------
template <class Epi>
__global__ __launch_bounds__(256) void k_gemm(const i8* __restrict__ A, const i8* __restrict__ B,
                                              int M, int N, int K, Epi epi) {
  __shared__ __align__(16) i8 As[3][8192];
  __shared__ __align__(16) i8 Bs[3][8192];
  const int tid = threadIdx.x;
  const int lane = tid & 63, wave = tid >> 6;
  const int quad = lane >> 4, lc = lane & 15;
  const int wr = wave >> 1, wc = wave & 1;
  const long bm = (long)blockIdx.y * 128, bn = (long)blockIdx.x * 128;
  const v4i vz = {0, 0, 0, 0};
  v4i acc[4][4];
#pragma unroll
  for (int i = 0; i < 4; i++)
#pragma unroll
    for (int j = 0; j < 4; j++) acc[i][j] = vz;

  // staging: thread stages LDS rows r0, r0+64, chunk c0. Source chunk is
  // XOR-swizzled so linear LDS write yields LDS[r][c] = glob[r][c^f(r)],
  // f(r) = (r>>1)&3  (f(r0+64)==f(r0)).
  const int r0 = tid >> 2, c0 = tid & 3;
  const int cs = c0 ^ ((r0 >> 1) & 3);
  long rA0 = bm + r0;      if (rA0 >= M) rA0 = 0;
  long rA1 = bm + r0 + 64; if (rA1 >= M) rA1 = 0;
  const i8* pA0 = A + rA0 * (size_t)K + cs * 16;
  const i8* pA1 = A + rA1 * (size_t)K + cs * 16;
  const i8* pB0 = B + (bn + r0)      * (size_t)K + cs * 16;
  const i8* pB1 = B + (bn + r0 + 64) * (size_t)K + cs * 16;

  auto stage = [&](int buf) {
    gload16(pA0, As[buf] + tid * 16); gload16(pA1, As[buf] + 4096 + tid * 16);
    gload16(pB0, Bs[buf] + tid * 16); gload16(pB1, Bs[buf] + 4096 + tid * 16);
    pA0 += 64; pA1 += 64; pB0 += 64; pB1 += 64;
  };

  // read-side swizzle: rows wr*64+i*16+lc (base%16==0) -> f(row)=(lc>>1)&3
  const int xq16 = (quad ^ ((lc >> 1) & 3)) * 16;

  auto compute = [&](int buf) {
    v4i af[4], bf[4];
#pragma unroll
    for (int i = 0; i < 4; i++) af[i] = *(const v4i*)(As[buf] + (wr * 64 + i * 16 + lc) * 64 + xq16);
#pragma unroll
    for (int j = 0; j < 4; j++) bf[j] = *(const v4i*)(Bs[buf] + (wc * 64 + j * 16 + lc) * 64 + xq16);
#pragma unroll
    for (int i = 0; i < 4; i++)
#pragma unroll
      for (int j = 0; j < 4; j++)   // swapped operands: acc row ~ N, col ~ M
        acc[i][j] = __builtin_amdgcn_mfma_i32_16x16x64_i8(bf[j], af[i], acc[i][j], 0, 0, 0);
  };

  const int nt = K >> 6;
  stage(0); stage(1);               // tiles 0,1 in flight (8 loads/wave)
  int cb = 0, sb = 2;
  for (int t = 0; t < nt - 1; ++t) {
    // own 4 oldest (tile t) retired; tile t+1's 4 stay in flight
    asm volatile("s_waitcnt vmcnt(4)" ::: "memory");
    __builtin_amdgcn_s_barrier();
    asm volatile("" ::: "memory");
    if (t + 2 < nt) { stage(sb); if (++sb == 3) sb = 0; }
    compute(cb); if (++cb == 3) cb = 0;
  }
  asm volatile("s_waitcnt vmcnt(0)" ::: "memory");
  __builtin_amdgcn_s_barrier();
  asm volatile("" ::: "memory");
  compute(cb);

  Epi e = epi;
  e.init();
#pragma unroll
  for (int i = 0; i < 4; i++) {
    int gm = (int)bm + wr * 64 + i * 16 + lc;          // col of D' = M row
#pragma unroll
    for (int j = 0; j < 4; j++) {
      int gn0 = (int)bn + wc * 64 + j * 16 + quad * 4; // row of D' = N col
      if (gm < M) e.store4(acc[i][j], gm, gn0);
    }
  }
}

// -------- epilogues: store4(a, m, n0) with a[r] = C[m][n0+r], n0%4==0 ----
struct EpiQKV {   // split into q,k (token-major) and v^T (ch-major, stride 256)
  const float* as; const float* wsc; const float* bias;
  i8 *qq, *kq, *vt;
  float sab, invq, invk, invv;
  __device__ void init() {
    sab = as[4] * wsc[0]; invq = 1.f / as[0]; invk = 1.f / as[1]; invv = 1.f / as[2];
  }
  __device__ void store4(const v4i a, int m, int n0) {
    int t = n0 / 768, rem = n0 - t * 768;
    int head = rem >> 6, ch0 = rem & 63;              // ch0%4==0: same head for all 4
    int win = m / 196, tok = m - win * 196;
    size_t bh = (size_t)win * 12 + head;
    float4 bv = *(const float4*)(bias + n0);
    const float* bp = (const float*)&bv;
    if (t == 2) {
#pragma unroll
      for (int r = 0; r < 4; r++)
        vt[(bh * 64 + ch0 + r) * 256 + tok] = satq(((float)a[r] * sab + bp[r]) * invv);
    } else {
      float inv = (t == 0) ? invq : invk;
      i8 q[4];
#pragma unroll
      for (int r = 0; r < 4; r++) q[r] = satq(((float)a[r] * sab + bp[r]) * inv);
      *(int*)((t == 0 ? qq : kq) + (bh * 196 + tok) * 64 + ch0) = pack4(q);
    }
  }
};

struct EpiProj {  // window reverse + unpad + shortcut add -> x2 (in d_out)
  const float* as; const float* wsc; const float* bias; const float* x0; float* out;
  float sab;
  __device__ void init() { sab = as[5] * wsc[1]; }
  __device__ void store4(const v4i a, int m, int n0) {
    int win = m / 196, tok = m - win * 196;
    int bb = win / 25, wrem = win - bb * 25, wh = wrem / 5, ww = wrem - wh * 5;
    int rr = tok / 14, cc = tok - rr * 14;
    int y = wh * 14 + rr, xx = ww * 14 + cc;
    if (y >= 64 || xx >= 64) return;
    size_t o = (((size_t)bb * 64 + y) * 64 + xx) * 768 + n0;
    float4 bv = *(const float4*)(bias + n0);
    float4 xv = *(const float4*)(x0 + o);
    float4 ov;
    ov.x = (float)a[0] * sab + bv.x + xv.x;
    ov.y = (float)a[1] * sab + bv.y + xv.y;
    ov.z = (float)a[2] * sab + bv.z + xv.z;
    ov.w = (float)a[3] * sab + bv.w + xv.w;
    *(float4*)(out + o) = ov;
  }
};

struct EpiLin1 {  // bias + branch-free gelu + quant a_s[7]
  const float* as; const float* wsc; const float* bias; i8* outq;
  float sab, invg;
  __device__ void init() { sab = as[6] * wsc[2]; invg = 1.f / as[7]; }
  __device__ void store4(const v4i a, int m, int n0) {
    float4 bv = *(const float4*)(bias + n0);
    const float* bp = (const float*)&bv;
    i8 q[4];
#pragma unroll
    for (int r = 0; r < 4; r++) {
      float v = fmaf((float)a[r], sab, bp[r]);
      q[r] = satq(fast_gelu(v) * invg);
    }
    *(int*)(outq + (size_t)m * 3072 + n0) = pack4(q);
  }
};

struct EpiLin2 {  // bias + residual add into d_out
  const float* as; const float* wsc; const float* bias; float* out;
  float sab;
  __device__ void init() { sab = as[7] * wsc[3]; }
  __device__ void store4(const v4i a, int m, int n0) {
    size_t o = (size_t)m * 768 + n0;
    float4 bv = *(const float4*)(bias + n0);
    float4 ov = *(const float4*)(out + o);
    ov.x += (float)a[0] * sab + bv.x;
    ov.y += (float)a[1] * sab + bv.y;
    ov.z += (float)a[2] * sab + bv.z;
    ov.w += (float)a[3] * sab + bv.w;
    *(float4*)(out + o) = ov;
  }
};

// ---------------------------------------------------------------------------
// attention: ONE WAVE per (win*12+head, 16-row tile). Grid (13, 1200), 64 thr.
// R5: swapped QK^T (mfma(K,Q)) -> lane holds the full P-row for q = lane&15:
//   softmax reduce = in-lane over 52 regs + shfl_xor(16)+(32) across quads;
//   P quantized to packed words in registers; PV A-fragments built by an
//   in-register 4x4 quad-word transpose (2-stage butterfly, 8 shfl_xor/kc).
//   P never touches LDS (was 208 ds_write_b8 + 16 ds_read_b128 per wave).
// Rel-pos bias via bf16 MFMA -> relS (only remaining LDS use).
// ---------------------------------------------------------------------------
__global__ __launch_bounds__(64, 4) void k_attn(const i8* __restrict__ qq, const i8* __restrict__ kq,
    const i8* __restrict__ vt, const short* __restrict__ TB,
    const float* __restrict__ as, i8* __restrict__ outq) {
  __shared__ float relS[16][66];                  // rel bias [q-row][d(h)|32+d(w)]
  const int t = blockIdx.x, bh = blockIdx.y;
  const int win = bh / 12, head = bh - win * 12;
  const int lane = threadIdx.x;
  const int quad = lane >> 4, lc = lane & 15;
  const float s0 = as[0];
  const float ssc = s0 * as[1] * 0.125f;
  const float invs3 = 1.0f / as[3];
  const float oscale = as[2] * as[3] / as[5];

  const v8s* TBv = (const v8s*)TB;
  const v4i vz = {0, 0, 0, 0};

  // ---- rel-pos bias via bf16 MFMA (writes relS[row=quad*4+r][...]) ----
  {
    int arow = t * 16 + lc; if (arow > 195) arow = 195;
    const i8* qrow = qq + ((size_t)bh * 196 + arow) * 64;
    v8s af[2];
#pragma unroll
    for (int ks = 0; ks < 2; ks++) {
      const i8* p = qrow + ks * 32 + quad * 8;
#pragma unroll
      for (int j = 0; j < 8; j++)
        af[ks][j] = (short)(__float_as_uint((float)p[j]) >> 16);  // exact int->bf16
    }
    v4f rh0 = {0,0,0,0}, rh1 = {0,0,0,0}, rw0 = {0,0,0,0}, rw1 = {0,0,0,0};
#pragma unroll
    for (int ks = 0; ks < 2; ks++)
#pragma unroll
      for (int p2 = 0; p2 < 2; p2++) {
        rh0 = __builtin_amdgcn_mfma_f32_16x16x32_bf16(af[ks], TBv[(0*4 + ks*2 + p2)*64 + lane], rh0, 0, 0, 0);
        rh1 = __builtin_amdgcn_mfma_f32_16x16x32_bf16(af[ks], TBv[(1*4 + ks*2 + p2)*64 + lane], rh1, 0, 0, 0);
        rw0 = __builtin_amdgcn_mfma_f32_16x16x32_bf16(af[ks], TBv[(2*4 + ks*2 + p2)*64 + lane], rw0, 0, 0, 0);
        rw1 = __builtin_amdgcn_mfma_f32_16x16x32_bf16(af[ks], TBv[(3*4 + ks*2 + p2)*64 + lane], rw1, 0, 0, 0);
      }
#pragma unroll
    for (int r = 0; r < 4; r++) {
      int rl = quad * 4 + r;
      relS[rl][lc]      = rh0[r] * s0;
      relS[rl][16 + lc] = rh1[r] * s0;
      relS[rl][32 + lc] = rw0[r] * s0;
      relS[rl][48 + lc] = rw1[r] * s0;
    }
  }

  // ---- QK^T, SWAPPED (int-exact): S^T[k][q], lane owns q = lc ----
  // sacc[f] = mfma(K-rows f*16+lc, Q-rows t*16+lc): D row = k = f*16+quad*4+r,
  // col = q = lc  ->  lane (quad,lc) holds P-row q=lc at k = f*16+quad*4+r.
  v4i aq = *(const v4i*)(qq + ((size_t)bh * 196 + t * 16 + lc) * 64 + quad * 16);
  v4i sacc[13];
#pragma unroll
  for (int f = 0; f < 13; f++) {
    v4i bk = *(const v4i*)(kq + ((size_t)bh * 196 + f * 16 + lc) * 64 + quad * 16);
    sacc[f] = __builtin_amdgcn_mfma_i32_16x16x64_i8(bk, aq, vz, 0, 0, 0);
  }

  // per-reg (kh<<4|kw) nibble table: compile-time constants selected by quad
  unsigned khw[13];
#pragma unroll
  for (int f = 0; f < 13; f++) {
    unsigned w0 = 0, w1 = 0, w2 = 0, w3 = 0;
#pragma unroll
    for (int r = 0; r < 4; r++) {
      int k0 = f*16 + 0*4 + r; if (k0 > 195) k0 = 195;
      int k1 = f*16 + 1*4 + r; if (k1 > 195) k1 = 195;
      int k2 = f*16 + 2*4 + r; if (k2 > 195) k2 = 195;
      int k3 = f*16 + 3*4 + r; if (k3 > 195) k3 = 195;
      w0 |= (unsigned)(((k0/14) << 4) | (k0 - (k0/14)*14)) << (r*8);
      w1 |= (unsigned)(((k1/14) << 4) | (k1 - (k1/14)*14)) << (r*8);
      w2 |= (unsigned)(((k2/14) << 4) | (k2 - (k2/14)*14)) << (r*8);
      w3 |= (unsigned)(((k3/14) << 4) | (k3 - (k3/14)*14)) << (r*8);
    }
    khw[f] = quad == 0 ? w0 : quad == 1 ? w1 : quad == 2 ? w2 : w3;
  }

  // ---- softmax (per-lane row q = lc) ----
  int qrow = t * 16 + lc;                       // may be >=196 for t=12: junk, store-guarded
  int qh = qrow / 14, qw = qrow - qh * 14;
  const float* rH = &relS[lc][13 + qh];         // rH[-kh]
  const float* rW = &relS[lc][32 + 13 + qw];    // rW[-kw]
  float L[13][4];
  float mx = -1e30f;
#pragma unroll
  for (int f = 0; f < 13; f++)
#pragma unroll
    for (int r = 0; r < 4; r++) {
      int kh = (int)((khw[f] >> (r * 8 + 4)) & 0xfu);
      int kw = (int)((khw[f] >> (r * 8)) & 0xfu);
      // valid: k = f*16+quad*4+r < 196  <=>  f<12 || quad==0
      float v = ((f < 12) | (quad == 0))
                  ? fmaf((float)sacc[f][r], ssc, rH[-kh] + rW[-kw]) : -1e30f;
      L[f][r] = v;
      mx = fmaxf(mx, v);
    }
  mx = fmaxf(mx, __shfl_xor(mx, 16));
  mx = fmaxf(mx, __shfl_xor(mx, 32));
  float sum = 0.f;
#pragma unroll
  for (int f = 0; f < 13; f++)
#pragma unroll
    for (int r = 0; r < 4; r++) { float e = __expf(L[f][r] - mx); L[f][r] = e; sum += e; }
  sum += __shfl_xor(sum, 16);
  sum += __shfl_xor(sum, 32);
  float cq = (1.0f / sum) * invs3;

  // quantize P to packed words: W[f] = P[q=lc][f*16+quad*4 .. +4]
  unsigned W[16];
#pragma unroll
  for (int f = 0; f < 13; f++) {
    i8 q4[4];
#pragma unroll
    for (int r = 0; r < 4; r++) q4[r] = satq(L[f][r] * cq);
    W[f] = (unsigned)pack4(q4);
  }
  W[13] = 0; W[14] = 0; W[15] = 0;

  // ---- PV (int-exact), A-frags from registers via 4x4 quad-word transpose ----
  v4i oacc[4];
#pragma unroll
  for (int nt = 0; nt < 4; nt++) oacc[nt] = vz;
  const bool q0m = (quad & 1) == 0, q1m = (quad & 2) == 0;
#pragma unroll
  for (int kc = 0; kc < 4; kc++) {
    unsigned a0 = W[kc*4+0], a1 = W[kc*4+1], a2 = W[kc*4+2], a3 = W[kc*4+3];
    // stage 1: exchange j-bit0 <-> quad-bit0 (lanes xor 16)
    unsigned s0_ = (unsigned)__shfl_xor((int)a1, 16);
    unsigned s1_ = (unsigned)__shfl_xor((int)a0, 16);
    unsigned s2_ = (unsigned)__shfl_xor((int)a3, 16);
    unsigned s3_ = (unsigned)__shfl_xor((int)a2, 16);
    unsigned x0 = q0m ? a0 : s0_;
    unsigned x1 = q0m ? s1_ : a1;
    unsigned x2 = q0m ? a2 : s2_;
    unsigned x3 = q0m ? s3_ : a3;
    // stage 2: exchange j-bit1 <-> quad-bit1 (lanes xor 32)
    unsigned u0 = (unsigned)__shfl_xor((int)x2, 32);
    unsigned u1 = (unsigned)__shfl_xor((int)x3, 32);
    unsigned u2 = (unsigned)__shfl_xor((int)x0, 32);
    unsigned u3 = (unsigned)__shfl_xor((int)x1, 32);
    v4i ap;
    ap[0] = (int)(q1m ? x0 : u0);
    ap[1] = (int)(q1m ? x1 : u1);
    ap[2] = (int)(q1m ? u2 : x2);
    ap[3] = (int)(q1m ? u3 : x3);
    // ap byte j = P[q=lc][kc*64 + quad*16 + j]  (A-frag for this kc)
#pragma unroll
    for (int nt = 0; nt < 4; nt++) {
      v4i bv = *(const v4i*)(vt + ((size_t)bh * 64 + nt * 16 + lc) * 256 + kc * 64 + quad * 16);
      oacc[nt] = __builtin_amdgcn_mfma_i32_16x16x64_i8(ap, bv, oacc[nt], 0, 0, 0);
    }
  }
#pragma unroll
  for (int nt = 0; nt < 4; nt++) {
    int ch = nt * 16 + lc;
#pragma unroll
    for (int r = 0; r < 4; r++) {
      int row = t * 16 + quad * 4 + r;
      if (row < 196)
        outq[((size_t)win * 196 + row) * 768 + head * 64 + ch] = satq((float)oacc[nt][r] * oscale);
    }
  }
}

// ---------------------------------------------------------------------------
extern "C" void kernel_launch(void* const* d_in, const int* in_sizes, int n_in,
                              void* d_out, int out_size, void* d_ws, size_t ws_size,
                              hipStream_t stream) {
  const float* x     = (const float*)d_in[0];
  const float* ln1w  = (const float*)d_in[1];
  const float* ln1b  = (const float*)d_in[2];
  const float* ln2w  = (const float*)d_in[3];
  const float* ln2b  = (const float*)d_in[4];
  const float* qkvw  = (const float*)d_in[5];
  const float* qkvb  = (const float*)d_in[6];
  const float* projw = (const float*)d_in[7];
  const float* projb = (const float*)d_in[8];
  const float* lin1w = (const float*)d_in[9];
  const float* lin1b = (const float*)d_in[10];
  const float* lin2w = (const float*)d_in[11];
  const float* lin2b = (const float*)d_in[12];
  const float* rph   = (const float*)d_in[13];
  const float* rpw   = (const float*)d_in[14];
  const float* as    = (const float*)d_in[15];
  const float* wsc   = (const float*)d_in[16];
  float* out = (float*)d_out;

  // ws layout (72,462,336 B total), regions reused across stages:
  char* ws = (char*)d_ws;
  i8* big    = (i8*)ws;                          // 50,331,648
  i8* qq     = big;                              // 15,052,800 (1200*196*64)
  i8* kq     = big + 15052800;                   // 15,052,800
  i8* vt     = big + 30105600;                   // 19,660,800 (1200*64*256)
  short* TB  = (short*)(big + 49766400);         //     16,384 (rel tables; dead before lin1)
  i8* mlpq   = big;                              // 50,331,648 (16384*3072), after attn
  i8* creg   = (i8*)(ws + 50331648);             // 15,052,800
  i8* winq   = creg;                             // qkv input
  i8* attno  = creg;                             // proj input (after qkv dead)
  i8* yq     = creg;                             // lin1 input (after proj dead)
  i8* wqb    = (i8*)(ws + 65384448);             //  7,077,888 (all 4 wq, contiguous)
  i8* qkvwq  = wqb;
  i8* projwq = wqb + 1769472;
  i8* lin1wq = projwq + 589824;
  i8* lin2wq = lin1wq + 2359296;

  k_prep<<<1732, 256, 0, stream>>>(qkvw, projw, lin1w, lin2w, wqb, rph, rpw, TB, wsc);

  k_ln1<<<4900, 256, 0, stream>>>(x, ln1w, ln1b, as, winq);

  { EpiQKV e{as, wsc, qkvb, qq, kq, vt};
    k_gemm<EpiQKV><<<dim3(18, 154), 256, 0, stream>>>(winq, qkvwq, 19600, 2304, 768, e); }

  k_attn<<<dim3(13, 1200), 64, 0, stream>>>(qq, kq, vt, TB, as, attno);

  { EpiProj e{as, wsc, projb, x, out};
    k_gemm<EpiProj><<<dim3(6, 154), 256, 0, stream>>>(attno, projwq, 19600, 768, 768, e); }

  k_ln2<<<4096, 256, 0, stream>>>(out, ln2w, ln2b, as, yq);

  { EpiLin1 e{as, wsc, lin1b, mlpq};
    k_gemm<EpiLin1><<<dim3(24, 128), 256, 0, stream>>>(yq, lin1wq, 16384, 3072, 768, e); }

  { EpiLin2 e{as, wsc, lin2b, out};
    k_gemm<EpiLin2><<<dim3(6, 128), 256, 0, stream>>>(mlpq, lin2wq, 16384, 768, 3072, e); }
}

// Round 6
// 517.481 us; speedup vs baseline: 1.0066x; 1.0066x over previous
//
#include <hip/hip_runtime.h>
#include <cstdint>

// ============================================================================
// QunatEncoderBlock: windowed attention block with int8 fake-quant.
// All qlinear / QK^T / PV matmuls are EXACT in int8xint8->int32 (MFMA i8).
// Rel-pos bias via bf16 MFMA with hi/lo split tables (error ~2^-18).
// R1: k_attn 1-wave/1-tile blocks. R2: branch-free erf gelu (lin1 99->89).
// R3: gemm chunk-XOR swizzle (conflicts 4.7M->0) + depth-2 vmcnt pipeline.
// R4: 8-phase 256^2 port regressed (1 block/CU) -> reverted to R3 gemm.
// R5: k_attn swapped-QK^T register-resident P (no P LDS tile); k_prep fusion.
//     -> EXPOSED: k_attn is HBM-bound: 200MB fetch + 128MB write/dispatch
//     (13 t-blocks of a bh round-robin across 8 XCDs -> per-XCD L2 refetch;
//     scattered byte stores -> write amplification).
// R6: (a) XCD-colocating bijective remap (15600 = 8*1950): all 13 t-blocks
//     of one bh land on ONE XCD, adjacent in order -> K/V/Q fetched once.
//     (b) PV operand swap mfma(V^T,P): lane holds 4 consecutive ch -> output
//     is 4 packed dword stores (was 16 scattered byte stores).
// ============================================================================

typedef int   v4i __attribute__((ext_vector_type(4)));
typedef float v4f __attribute__((ext_vector_type(4)));
typedef short v8s __attribute__((ext_vector_type(8)));
typedef int8_t i8;

__device__ __forceinline__ i8 satq(float x) {   // x already scale-divided
  float q = rintf(x);
  q = fminf(127.f, fmaxf(-128.f, q));
  return (i8)(int)q;
}

__device__ __forceinline__ void gload16(const i8* g, i8* l) {
  __builtin_amdgcn_global_load_lds((const __attribute__((address_space(1))) void*)g,
                                   (__attribute__((address_space(3))) void*)l, 16, 0, 0);
}

__device__ __forceinline__ int pack4(const i8* q) {
  return ((int)(unsigned char)q[0]) | ((int)(unsigned char)q[1] << 8) |
         ((int)(unsigned char)q[2] << 16) | ((int)(unsigned char)q[3] << 24);
}

// branch-free gelu: 0.5*v*(1+erf(v/sqrt2)), erf via A-S 7.1.26 (|err|<=1.5e-7)
__device__ __forceinline__ float fast_gelu(float v) {
  float x = fabsf(v) * 0.70710678118654752f;
  float t = __builtin_amdgcn_rcpf(fmaf(0.3275911f, x, 1.0f));
  float s = fmaf(1.061405429f, t, -1.453152027f);
  s = fmaf(s, t, 1.421413741f);
  s = fmaf(s, t, -0.284496736f);
  s = fmaf(s, t, 0.254829592f);
  s = s * t;
  float e = __expf(-x * x);
  float erfa = fmaf(-s, e, 1.0f);          // erf(|x|)
  float erfs = copysignf(erfa, v);
  float hv = 0.5f * v;
  return fmaf(hv, erfs, hv);
}

// ---------------------------------------------------------------------------
// k_prep: all 4 weight fake-quants (outputs contiguous in wqb, 256-aligned
// region boundaries -> block-uniform) + rel-pos table pack, one launch.
// ---------------------------------------------------------------------------
__global__ __launch_bounds__(256) void k_prep(const float* __restrict__ qkvw,
    const float* __restrict__ projw, const float* __restrict__ lin1w,
    const float* __restrict__ lin2w, i8* __restrict__ wqb,
    const float* __restrict__ rph, const float* __restrict__ rpw,
    short* __restrict__ TB, const float* __restrict__ wsc) {
  int b = blockIdx.x;
  if (b < 1728) {
    int i = b * 256 + threadIdx.x;          // < 442368
    const float* w; int base, sidx;
    if (i < 110592)      { w = qkvw;  base = 0;      sidx = 0; }
    else if (i < 147456) { w = projw; base = 110592; sidx = 1; }
    else if (i < 294912) { w = lin1w; base = 147456; sidx = 2; }
    else                 { w = lin2w; base = 294912; sidx = 3; }
    float inv = 1.0f / wsc[sidx];
    const float4* src = (const float4*)w + (size_t)(i - base) * 4;
    i8 buf[16];
#pragma unroll
    for (int t = 0; t < 4; t++) {
      float4 f = src[t];
      buf[t*4+0] = satq(f.x * inv); buf[t*4+1] = satq(f.y * inv);
      buf[t*4+2] = satq(f.z * inv); buf[t*4+3] = satq(f.w * inv);
    }
    *(v4i*)(wqb + (size_t)i * 16) = *(v4i*)buf;
  } else {
    int g = (b - 1728) * 256 + threadIdx.x;  // < 1024
    int lane = g & 63, c = g >> 6;
    int p = c & 1, ks = (c >> 1) & 1, nt = (c >> 2) & 1, tb = c >> 3;
    const float* src = tb ? rpw : rph;
    int n = nt * 16 + (lane & 15);
    int k0 = ks * 32 + (lane >> 4) * 8;
    short outv[8];
#pragma unroll
    for (int j = 0; j < 8; j++) {
      float v = (n < 27) ? src[n * 64 + k0 + j] : 0.f;
      unsigned u = __float_as_uint(v);
      unsigned hi = (u + 0x7fffu + ((u >> 16) & 1u)) >> 16;
      if (p == 0) outv[j] = (short)hi;
      else {
        float lof = v - __uint_as_float(hi << 16);
        unsigned ul = __float_as_uint(lof);
        outv[j] = (short)((ul + 0x7fffu + ((ul >> 16) & 1u)) >> 16);
      }
    }
    *(v8s*)(TB + (size_t)c * 512 + lane * 8) = *(v8s*)outv;
  }
}

// ---------------------------------------------------------------------------
// LN1: wave per window-token (pad 64->70, 5x5 windows of 14x14), quant a_s[4]
// ---------------------------------------------------------------------------
__global__ __launch_bounds__(256) void k_ln1(const float* __restrict__ x,
    const float* __restrict__ w, const float* __restrict__ b,
    const float* __restrict__ as, i8* __restrict__ outq) {
  int wt = blockIdx.x * 4 + (threadIdx.x >> 6);
  int lane = threadIdx.x & 63;
  int win = wt / 196, tok = wt - win * 196;
  int bb = win / 25, wrem = win - bb * 25, wh = wrem / 5, ww = wrem - wh * 5;
  int r = tok / 14, c = tok - r * 14;
  int y = wh * 14 + r, xx = ww * 14 + c;
  i8* dst = outq + (size_t)wt * 768 + lane * 12;
  if (y >= 64 || xx >= 64) {
    ((int*)dst)[0] = 0; ((int*)dst)[1] = 0; ((int*)dst)[2] = 0;
    return;
  }
  const float* row = x + (((size_t)bb * 64 + y) * 64 + xx) * 768 + lane * 12;
  float v[12];
  *(float4*)(v)     = *(const float4*)(row);
  *(float4*)(v + 4) = *(const float4*)(row + 4);
  *(float4*)(v + 8) = *(const float4*)(row + 8);
  float s = 0.f, ss = 0.f;
#pragma unroll
  for (int j = 0; j < 12; j++) { s += v[j]; ss += v[j] * v[j]; }
#pragma unroll
  for (int off = 1; off < 64; off <<= 1) { s += __shfl_xor(s, off); ss += __shfl_xor(ss, off); }
  float mu = s * (1.0f / 768.0f);
  float var = ss * (1.0f / 768.0f) - mu * mu;
  float rstd = 1.0f / sqrtf(var + 1e-6f);
  float inv = 1.0f / as[4];
  float wv[12], bv[12];
  *(float4*)(wv)     = *(const float4*)(w + lane * 12);
  *(float4*)(wv + 4) = *(const float4*)(w + lane * 12 + 4);
  *(float4*)(wv + 8) = *(const float4*)(w + lane * 12 + 8);
  *(float4*)(bv)     = *(const float4*)(b + lane * 12);
  *(float4*)(bv + 4) = *(const float4*)(b + lane * 12 + 4);
  *(float4*)(bv + 8) = *(const float4*)(b + lane * 12 + 8);
  i8 q[12];
#pragma unroll
  for (int j = 0; j < 12; j++) q[j] = satq(((v[j] - mu) * rstd * wv[j] + bv[j]) * inv);
  ((int*)dst)[0] = pack4(q); ((int*)dst)[1] = pack4(q + 4); ((int*)dst)[2] = pack4(q + 8);
}

// ---------------------------------------------------------------------------
// LN2: wave per token, quant a_s[6]
// ---------------------------------------------------------------------------
__global__ __launch_bounds__(256) void k_ln2(const float* __restrict__ x2,
    const float* __restrict__ w, const float* __restrict__ b,
    const float* __restrict__ as, i8* __restrict__ outq) {
  int tokg = blockIdx.x * 4 + (threadIdx.x >> 6);
  int lane = threadIdx.x & 63;
  const float* row = x2 + (size_t)tokg * 768 + lane * 12;
  float v[12];
  *(float4*)(v)     = *(const float4*)(row);
  *(float4*)(v + 4) = *(const float4*)(row + 4);
  *(float4*)(v + 8) = *(const float4*)(row + 8);
  float s = 0.f, ss = 0.f;
#pragma unroll
  for (int j = 0; j < 12; j++) { s += v[j]; ss += v[j] * v[j]; }
#pragma unroll
  for (int off = 1; off < 64; off <<= 1) { s += __shfl_xor(s, off); ss += __shfl_xor(ss, off); }
  float mu = s * (1.0f / 768.0f);
  float var = ss * (1.0f / 768.0f) - mu * mu;
  float rstd = 1.0f / sqrtf(var + 1e-6f);
  float inv = 1.0f / as[6];
  float wv[12], bv[12];
  *(float4*)(wv)     = *(const float4*)(w + lane * 12);
  *(float4*)(wv + 4) = *(const float4*)(w + lane * 12 + 4);
  *(float4*)(wv + 8) = *(const float4*)(w + lane * 12 + 8);
  *(float4*)(bv)     = *(const float4*)(b + lane * 12);
  *(float4*)(bv + 4) = *(const float4*)(b + lane * 12 + 4);
  *(float4*)(bv + 8) = *(const float4*)(b + lane * 12 + 8);
  i8* dst = outq + (size_t)tokg * 768 + lane * 12;
  i8 q[12];
#pragma unroll
  for (int j = 0; j < 12; j++) q[j] = satq(((v[j] - mu) * rstd * wv[j] + bv[j]) * inv);
  ((int*)dst)[0] = pack4(q); ((int*)dst)[1] = pack4(q + 4); ((int*)dst)[2] = pack4(q + 8);
}

// ---------------------------------------------------------------------------
// int8 GEMM: C[M,N] = A[M,K] x B[N,K]^T, 128x128 tile, BK=64.  [R3 version]
// depth-2 pipeline, 3 LDS buffers, counted vmcnt, raw barriers,
// chunk-XOR swizzle, operand-swapped MFMA. N%128==0, K%64==0, K>=128.
// Epi::store4(a, m, n0): a[r] = C[m][n0+r], n0%4==0, m<M guaranteed.
// ---------------------------------------------------------------------------
template <class Epi>
__global__ __launch_bounds__(256) void k_gemm(const i8* __restrict__ A, const i8* __restrict__ B,
                                              int M, int N, int K, Epi epi) {
  __shared__ __align__(16) i8 As[3][8192];
  __shared__ __align__(16) i8 Bs[3][8192];
  const int tid = threadIdx.x;
  const int lane = tid & 63, wave = tid >> 6;
  const int quad = lane >> 4, lc = lane & 15;
  const int wr = wave >> 1, wc = wave & 1;
  const long bm = (long)blockIdx.y * 128, bn = (long)blockIdx.x * 128;
  const v4i vz = {0, 0, 0, 0};
  v4i acc[4][4];
#pragma unroll
  for (int i = 0; i < 4; i++)
#pragma unroll
    for (int j = 0; j < 4; j++) acc[i][j] = vz;

  const int r0 = tid >> 2, c0 = tid & 3;
  const int cs = c0 ^ ((r0 >> 1) & 3);
  long rA0 = bm + r0;      if (rA0 >= M) rA0 = 0;
  long rA1 = bm + r0 + 64; if (rA1 >= M) rA1 = 0;
  const i8* pA0 = A + rA0 * (size_t)K + cs * 16;
  const i8* pA1 = A + rA1 * (size_t)K + cs * 16;
  const i8* pB0 = B + (bn + r0)      * (size_t)K + cs * 16;
  const i8* pB1 = B + (bn + r0 + 64) * (size_t)K + cs * 16;

  auto stage = [&](int buf) {
    gload16(pA0, As[buf] + tid * 16); gload16(pA1, As[buf] + 4096 + tid * 16);
    gload16(pB0, Bs[buf] + tid * 16); gload16(pB1, Bs[buf] + 4096 + tid * 16);
    pA0 += 64; pA1 += 64; pB0 += 64; pB1 += 64;
  };

  const int xq16 = (quad ^ ((lc >> 1) & 3)) * 16;

  auto compute = [&](int buf) {
    v4i af[4], bf[4];
#pragma unroll
    for (int i = 0; i < 4; i++) af[i] = *(const v4i*)(As[buf] + (wr * 64 + i * 16 + lc) * 64 + xq16);
#pragma unroll
    for (int j = 0; j < 4; j++) bf[j] = *(const v4i*)(Bs[buf] + (wc * 64 + j * 16 + lc) * 64 + xq16);
#pragma unroll
    for (int i = 0; i < 4; i++)
#pragma unroll
      for (int j = 0; j < 4; j++)   // swapped operands: acc row ~ N, col ~ M
        acc[i][j] = __builtin_amdgcn_mfma_i32_16x16x64_i8(bf[j], af[i], acc[i][j], 0, 0, 0);
  };

  const int nt = K >> 6;
  stage(0); stage(1);               // tiles 0,1 in flight (8 loads/wave)
  int cb = 0, sb = 2;
  for (int t = 0; t < nt - 1; ++t) {
    asm volatile("s_waitcnt vmcnt(4)" ::: "memory");
    __builtin_amdgcn_s_barrier();
    asm volatile("" ::: "memory");
    if (t + 2 < nt) { stage(sb); if (++sb == 3) sb = 0; }
    compute(cb); if (++cb == 3) cb = 0;
  }
  asm volatile("s_waitcnt vmcnt(0)" ::: "memory");
  __builtin_amdgcn_s_barrier();
  asm volatile("" ::: "memory");
  compute(cb);

  Epi e = epi;
  e.init();
#pragma unroll
  for (int i = 0; i < 4; i++) {
    int gm = (int)bm + wr * 64 + i * 16 + lc;          // M row
#pragma unroll
    for (int j = 0; j < 4; j++) {
      int gn0 = (int)bn + wc * 64 + j * 16 + quad * 4; // N col (4 consecutive)
      if (gm < M) e.store4(acc[i][j], gm, gn0);
    }
  }
}

// -------- epilogues: store4(a, m, n0) with a[r] = C[m][n0+r], n0%4==0 ----
struct EpiQKV {   // split into q,k (token-major) and v^T (ch-major, stride 256)
  const float* as; const float* wsc; const float* bias;
  i8 *qq, *kq, *vt;
  float sab, invq, invk, invv;
  __device__ void init() {
    sab = as[4] * wsc[0]; invq = 1.f / as[0]; invk = 1.f / as[1]; invv = 1.f / as[2];
  }
  __device__ void store4(const v4i a, int m, int n0) {
    int t = n0 / 768, rem = n0 - t * 768;
    int head = rem >> 6, ch0 = rem & 63;              // ch0%4==0: same head for all 4
    int win = m / 196, tok = m - win * 196;
    size_t bh = (size_t)win * 12 + head;
    float4 bv = *(const float4*)(bias + n0);
    const float* bp = (const float*)&bv;
    if (t == 2) {
#pragma unroll
      for (int r = 0; r < 4; r++)
        vt[(bh * 64 + ch0 + r) * 256 + tok] = satq(((float)a[r] * sab + bp[r]) * invv);
    } else {
      float inv = (t == 0) ? invq : invk;
      i8 q[4];
#pragma unroll
      for (int r = 0; r < 4; r++) q[r] = satq(((float)a[r] * sab + bp[r]) * inv);
      *(int*)((t == 0 ? qq : kq) + (bh * 196 + tok) * 64 + ch0) = pack4(q);
    }
  }
};

struct EpiProj {  // window reverse + unpad + shortcut add -> x2 (in d_out)
  const float* as; const float* wsc; const float* bias; const float* x0; float* out;
  float sab;
  __device__ void init() { sab = as[5] * wsc[1]; }
  __device__ void store4(const v4i a, int m, int n0) {
    int win = m / 196, tok = m - win * 196;
    int bb = win / 25, wrem = win - bb * 25, wh = wrem / 5, ww = wrem - wh * 5;
    int rr = tok / 14, cc = tok - rr * 14;
    int y = wh * 14 + rr, xx = ww * 14 + cc;
    if (y >= 64 || xx >= 64) return;
    size_t o = (((size_t)bb * 64 + y) * 64 + xx) * 768 + n0;
    float4 bv = *(const float4*)(bias + n0);
    float4 xv = *(const float4*)(x0 + o);
    float4 ov;
    ov.x = (float)a[0] * sab + bv.x + xv.x;
    ov.y = (float)a[1] * sab + bv.y + xv.y;
    ov.z = (float)a[2] * sab + bv.z + xv.z;
    ov.w = (float)a[3] * sab + bv.w + xv.w;
    *(float4*)(out + o) = ov;
  }
};

struct EpiLin1 {  // bias + branch-free gelu + quant a_s[7]
  const float* as; const float* wsc; const float* bias; i8* outq;
  float sab, invg;
  __device__ void init() { sab = as[6] * wsc[2]; invg = 1.f / as[7]; }
  __device__ void store4(const v4i a, int m, int n0) {
    float4 bv = *(const float4*)(bias + n0);
    const float* bp = (const float*)&bv;
    i8 q[4];
#pragma unroll
    for (int r = 0; r < 4; r++) {
      float v = fmaf((float)a[r], sab, bp[r]);
      q[r] = satq(fast_gelu(v) * invg);
    }
    *(int*)(outq + (size_t)m * 3072 + n0) = pack4(q);
  }
};

struct EpiLin2 {  // bias + residual add into d_out
  const float* as; const float* wsc; const float* bias; float* out;
  float sab;
  __device__ void init() { sab = as[7] * wsc[3]; }
  __device__ void store4(const v4i a, int m, int n0) {
    size_t o = (size_t)m * 768 + n0;
    float4 bv = *(const float4*)(bias + n0);
    float4 ov = *(const float4*)(out + o);
    ov.x += (float)a[0] * sab + bv.x;
    ov.y += (float)a[1] * sab + bv.y;
    ov.z += (float)a[2] * sab + bv.z;
    ov.w += (float)a[3] * sab + bv.w;
    *(float4*)(out + o) = ov;
  }
};

// ---------------------------------------------------------------------------
// attention: ONE WAVE per (bh, 16-row tile). Grid 15600 x 64 thr, with
// XCD-colocating bijective remap (15600 = 8*1950): xcd g&7 gets work ids
// [xcd*1950, (xcd+1)*1950) -> all 13 t-tiles of one bh on ONE XCD, adjacent.
// Swapped QK^T (register P) + swapped PV (packed dword output stores).
// ---------------------------------------------------------------------------
__global__ __launch_bounds__(64, 4) void k_attn(const i8* __restrict__ qq, const i8* __restrict__ kq,
    const i8* __restrict__ vt, const short* __restrict__ TB,
    const float* __restrict__ as, i8* __restrict__ outq) {
  __shared__ float relS[16][66];                  // rel bias [q-row][d(h)|32+d(w)]
  const int g = blockIdx.x;
  const int work = (g & 7) * 1950 + (g >> 3);    // bijective: 15600 = 8*1950
  const int bh = work / 13;
  const int t = work - bh * 13;
  const int win = bh / 12, head = bh - win * 12;
  const int lane = threadIdx.x;
  const int quad = lane >> 4, lc = lane & 15;
  const float s0 = as[0];
  const float ssc = s0 * as[1] * 0.125f;
  const float invs3 = 1.0f / as[3];
  const float oscale = as[2] * as[3] / as[5];

  const v8s* TBv = (const v8s*)TB;
  const v4i vz = {0, 0, 0, 0};

  // ---- rel-pos bias via bf16 MFMA (writes relS[row=quad*4+r][...]) ----
  {
    int arow = t * 16 + lc; if (arow > 195) arow = 195;
    const i8* qrow = qq + ((size_t)bh * 196 + arow) * 64;
    v8s af[2];
#pragma unroll
    for (int ks = 0; ks < 2; ks++) {
      const i8* p = qrow + ks * 32 + quad * 8;
#pragma unroll
      for (int j = 0; j < 8; j++)
        af[ks][j] = (short)(__float_as_uint((float)p[j]) >> 16);  // exact int->bf16
    }
    v4f rh0 = {0,0,0,0}, rh1 = {0,0,0,0}, rw0 = {0,0,0,0}, rw1 = {0,0,0,0};
#pragma unroll
    for (int ks = 0; ks < 2; ks++)
#pragma unroll
      for (int p2 = 0; p2 < 2; p2++) {
        rh0 = __builtin_amdgcn_mfma_f32_16x16x32_bf16(af[ks], TBv[(0*4 + ks*2 + p2)*64 + lane], rh0, 0, 0, 0);
        rh1 = __builtin_amdgcn_mfma_f32_16x16x32_bf16(af[ks], TBv[(1*4 + ks*2 + p2)*64 + lane], rh1, 0, 0, 0);
        rw0 = __builtin_amdgcn_mfma_f32_16x16x32_bf16(af[ks], TBv[(2*4 + ks*2 + p2)*64 + lane], rw0, 0, 0, 0);
        rw1 = __builtin_amdgcn_mfma_f32_16x16x32_bf16(af[ks], TBv[(3*4 + ks*2 + p2)*64 + lane], rw1, 0, 0, 0);
      }
#pragma unroll
    for (int r = 0; r < 4; r++) {
      int rl = quad * 4 + r;
      relS[rl][lc]      = rh0[r] * s0;
      relS[rl][16 + lc] = rh1[r] * s0;
      relS[rl][32 + lc] = rw0[r] * s0;
      relS[rl][48 + lc] = rw1[r] * s0;
    }
  }

  // ---- QK^T, SWAPPED (int-exact): lane (quad,lc) holds P-row q=lc at
  // k = f*16+quad*4+r ----
  v4i aq = *(const v4i*)(qq + ((size_t)bh * 196 + t * 16 + lc) * 64 + quad * 16);
  v4i sacc[13];
#pragma unroll
  for (int f = 0; f < 13; f++) {
    v4i bk = *(const v4i*)(kq + ((size_t)bh * 196 + f * 16 + lc) * 64 + quad * 16);
    sacc[f] = __builtin_amdgcn_mfma_i32_16x16x64_i8(bk, aq, vz, 0, 0, 0);
  }

  // per-reg (kh<<4|kw) nibble table: compile-time constants selected by quad
  unsigned khw[13];
#pragma unroll
  for (int f = 0; f < 13; f++) {
    unsigned w0 = 0, w1 = 0, w2 = 0, w3 = 0;
#pragma unroll
    for (int r = 0; r < 4; r++) {
      int k0 = f*16 + 0*4 + r; if (k0 > 195) k0 = 195;
      int k1 = f*16 + 1*4 + r; if (k1 > 195) k1 = 195;
      int k2 = f*16 + 2*4 + r; if (k2 > 195) k2 = 195;
      int k3 = f*16 + 3*4 + r; if (k3 > 195) k3 = 195;
      w0 |= (unsigned)(((k0/14) << 4) | (k0 - (k0/14)*14)) << (r*8);
      w1 |= (unsigned)(((k1/14) << 4) | (k1 - (k1/14)*14)) << (r*8);
      w2 |= (unsigned)(((k2/14) << 4) | (k2 - (k2/14)*14)) << (r*8);
      w3 |= (unsigned)(((k3/14) << 4) | (k3 - (k3/14)*14)) << (r*8);
    }
    khw[f] = quad == 0 ? w0 : quad == 1 ? w1 : quad == 2 ? w2 : w3;
  }

  // ---- softmax (per-lane row q = lc) ----
  int qrow = t * 16 + lc;                       // >=196 only for t=12: junk, store-guarded
  int qh = qrow / 14, qw = qrow - qh * 14;
  const float* rH = &relS[lc][13 + qh];         // rH[-kh]
  const float* rW = &relS[lc][32 + 13 + qw];    // rW[-kw]
  float L[13][4];
  float mx = -1e30f;
#pragma unroll
  for (int f = 0; f < 13; f++)
#pragma unroll
    for (int r = 0; r < 4; r++) {
      int kh = (int)((khw[f] >> (r * 8 + 4)) & 0xfu);
      int kw = (int)((khw[f] >> (r * 8)) & 0xfu);
      float v = ((f < 12) | (quad == 0))
                  ? fmaf((float)sacc[f][r], ssc, rH[-kh] + rW[-kw]) : -1e30f;
      L[f][r] = v;
      mx = fmaxf(mx, v);
    }
  mx = fmaxf(mx, __shfl_xor(mx, 16));
  mx = fmaxf(mx, __shfl_xor(mx, 32));
  float sum = 0.f;
#pragma unroll
  for (int f = 0; f < 13; f++)
#pragma unroll
    for (int r = 0; r < 4; r++) { float e = __expf(L[f][r] - mx); L[f][r] = e; sum += e; }
  sum += __shfl_xor(sum, 16);
  sum += __shfl_xor(sum, 32);
  float cq = (1.0f / sum) * invs3;

  // quantize P to packed words: W[f] = P[q=lc][f*16+quad*4 .. +4]
  unsigned W[16];
#pragma unroll
  for (int f = 0; f < 13; f++) {
    i8 q4[4];
#pragma unroll
    for (int r = 0; r < 4; r++) q4[r] = satq(L[f][r] * cq);
    W[f] = (unsigned)pack4(q4);
  }
  W[13] = 0; W[14] = 0; W[15] = 0;

  // ---- PV (int-exact), A-frags via in-register 4x4 quad-word transpose ----
  v4i oacc[4];
#pragma unroll
  for (int nt = 0; nt < 4; nt++) oacc[nt] = vz;
  const bool q0m = (quad & 1) == 0, q1m = (quad & 2) == 0;
#pragma unroll
  for (int kc = 0; kc < 4; kc++) {
    unsigned a0 = W[kc*4+0], a1 = W[kc*4+1], a2 = W[kc*4+2], a3 = W[kc*4+3];
    // stage 1: exchange j-bit0 <-> quad-bit0 (lanes xor 16)
    unsigned s0_ = (unsigned)__shfl_xor((int)a1, 16);
    unsigned s1_ = (unsigned)__shfl_xor((int)a0, 16);
    unsigned s2_ = (unsigned)__shfl_xor((int)a3, 16);
    unsigned s3_ = (unsigned)__shfl_xor((int)a2, 16);
    unsigned x0 = q0m ? a0 : s0_;
    unsigned x1 = q0m ? s1_ : a1;
    unsigned x2 = q0m ? a2 : s2_;
    unsigned x3 = q0m ? s3_ : a3;
    // stage 2: exchange j-bit1 <-> quad-bit1 (lanes xor 32)
    unsigned u0 = (unsigned)__shfl_xor((int)x2, 32);
    unsigned u1 = (unsigned)__shfl_xor((int)x3, 32);
    unsigned u2 = (unsigned)__shfl_xor((int)x0, 32);
    unsigned u3 = (unsigned)__shfl_xor((int)x1, 32);
    v4i ap;
    ap[0] = (int)(q1m ? x0 : u0);
    ap[1] = (int)(q1m ? x1 : u1);
    ap[2] = (int)(q1m ? u2 : x2);
    ap[3] = (int)(q1m ? u3 : x3);
    // ap byte j = P[q=lc][kc*64 + quad*16 + j]  (also valid as B-frag, row=lc)
#pragma unroll
    for (int nt = 0; nt < 4; nt++) {
      v4i bv = *(const v4i*)(vt + ((size_t)bh * 64 + nt * 16 + lc) * 256 + kc * 64 + quad * 16);
      // SWAPPED: A=V^T rows ch, B=P rows q -> lane holds O[q=lc][ch=nt*16+quad*4+r]
      oacc[nt] = __builtin_amdgcn_mfma_i32_16x16x64_i8(bv, ap, oacc[nt], 0, 0, 0);
    }
  }
  // packed dword stores: lane writes 4 consecutive ch of row q=t*16+lc
  if (t * 16 + lc < 196) {
    i8* orow = outq + ((size_t)win * 196 + t * 16 + lc) * 768 + head * 64 + quad * 4;
#pragma unroll
    for (int nt = 0; nt < 4; nt++) {
      i8 q4[4];
#pragma unroll
      for (int r = 0; r < 4; r++) q4[r] = satq((float)oacc[nt][r] * oscale);
      *(int*)(orow + nt * 16) = pack4(q4);
    }
  }
}

// ---------------------------------------------------------------------------
extern "C" void kernel_launch(void* const* d_in, const int* in_sizes, int n_in,
                              void* d_out, int out_size, void* d_ws, size_t ws_size,
                              hipStream_t stream) {
  const float* x     = (const float*)d_in[0];
  const float* ln1w  = (const float*)d_in[1];
  const float* ln1b  = (const float*)d_in[2];
  const float* ln2w  = (const float*)d_in[3];
  const float* ln2b  = (const float*)d_in[4];
  const float* qkvw  = (const float*)d_in[5];
  const float* qkvb  = (const float*)d_in[6];
  const float* projw = (const float*)d_in[7];
  const float* projb = (const float*)d_in[8];
  const float* lin1w = (const float*)d_in[9];
  const float* lin1b = (const float*)d_in[10];
  const float* lin2w = (const float*)d_in[11];
  const float* lin2b = (const float*)d_in[12];
  const float* rph   = (const float*)d_in[13];
  const float* rpw   = (const float*)d_in[14];
  const float* as    = (const float*)d_in[15];
  const float* wsc   = (const float*)d_in[16];
  float* out = (float*)d_out;

  // ws layout (72,462,336 B total), regions reused across stages:
  char* ws = (char*)d_ws;
  i8* big    = (i8*)ws;                          // 50,331,648
  i8* qq     = big;                              // 15,052,800 (1200*196*64)
  i8* kq     = big + 15052800;                   // 15,052,800
  i8* vt     = big + 30105600;                   // 19,660,800 (1200*64*256)
  short* TB  = (short*)(big + 49766400);         //     16,384 (rel tables; dead before lin1)
  i8* mlpq   = big;                              // 50,331,648 (16384*3072), after attn
  i8* creg   = (i8*)(ws + 50331648);             // 15,052,800
  i8* winq   = creg;                             // qkv input
  i8* attno  = creg;                             // proj input (after qkv dead)
  i8* yq     = creg;                             // lin1 input (after proj dead)
  i8* wqb    = (i8*)(ws + 65384448);             //  7,077,888 (all 4 wq, contiguous)
  i8* qkvwq  = wqb;
  i8* projwq = wqb + 1769472;
  i8* lin1wq = projwq + 589824;
  i8* lin2wq = lin1wq + 2359296;

  k_prep<<<1732, 256, 0, stream>>>(qkvw, projw, lin1w, lin2w, wqb, rph, rpw, TB, wsc);

  k_ln1<<<4900, 256, 0, stream>>>(x, ln1w, ln1b, as, winq);

  { EpiQKV e{as, wsc, qkvb, qq, kq, vt};
    k_gemm<EpiQKV><<<dim3(18, 154), 256, 0, stream>>>(winq, qkvwq, 19600, 2304, 768, e); }

  k_attn<<<15600, 64, 0, stream>>>(qq, kq, vt, TB, as, attno);

  { EpiProj e{as, wsc, projb, x, out};
    k_gemm<EpiProj><<<dim3(6, 154), 256, 0, stream>>>(attno, projwq, 19600, 768, 768, e); }

  k_ln2<<<4096, 256, 0, stream>>>(out, ln2w, ln2b, as, yq);

  { EpiLin1 e{as, wsc, lin1b, mlpq};
    k_gemm<EpiLin1><<<dim3(24, 128), 256, 0, stream>>>(yq, lin1wq, 16384, 3072, 768, e); }

  { EpiLin2 e{as, wsc, lin2b, out};
    k_gemm<EpiLin2><<<dim3(6, 128), 256, 0, stream>>>(mlpq, lin2wq, 16384, 768, 3072, e); }
}

// Round 7
// 509.308 us; speedup vs baseline: 1.0227x; 1.0160x over previous
//
#include <hip/hip_runtime.h>
#include <cstdint>

// ============================================================================
// QunatEncoderBlock: windowed attention block with int8 fake-quant.
// All qlinear / QK^T / PV matmuls are EXACT in int8xint8->int32 (MFMA i8).
// Rel-pos bias via bf16 MFMA with hi/lo split tables (error ~2^-18).
// R1: k_attn 1-wave/1-tile blocks. R2: branch-free erf gelu (lin1 99->89).
// R3: gemm chunk-XOR swizzle (conflicts 4.7M->0) + depth-2 vmcnt pipeline.
// R4: 8-phase 256^2 port regressed (1 block/CU) -> reverted to R3 gemm.
// R5: k_attn swapped-QK^T register-resident P; k_prep fusion.
// R6: XCD-colocating remap: FETCH 200->80MB. WRITE stuck at 131MB (8.8x):
//     each 64B output line filled by 16 partial stores -> L2 thrash.
//     dur == bytes/BW in R5+R6: k_attn is pure HBM-traffic-bound.
// R7: (a) attno layout -> [bh][tok][64]: block owns contiguous 1KB.
//     (b) in-register quad<->nt transpose of O (same butterfly as P) ->
//         ONE global_store_dwordx4 per lane: every 64B line written whole,
//         once, by one instruction. (c) proj GEMM AHEAD A-remap: reads
//         A[m][head*64+ch] from the head-major buffer (stride/base change
//         only; staging width unchanged).
// ============================================================================

typedef int   v4i __attribute__((ext_vector_type(4)));
typedef float v4f __attribute__((ext_vector_type(4)));
typedef short v8s __attribute__((ext_vector_type(8)));
typedef int8_t i8;

__device__ __forceinline__ i8 satq(float x) {   // x already scale-divided
  float q = rintf(x);
  q = fminf(127.f, fmaxf(-128.f, q));
  return (i8)(int)q;
}

__device__ __forceinline__ void gload16(const i8* g, i8* l) {
  __builtin_amdgcn_global_load_lds((const __attribute__((address_space(1))) void*)g,
                                   (__attribute__((address_space(3))) void*)l, 16, 0, 0);
}

__device__ __forceinline__ int pack4(const i8* q) {
  return ((int)(unsigned char)q[0]) | ((int)(unsigned char)q[1] << 8) |
         ((int)(unsigned char)q[2] << 16) | ((int)(unsigned char)q[3] << 24);
}

// branch-free gelu: 0.5*v*(1+erf(v/sqrt2)), erf via A-S 7.1.26 (|err|<=1.5e-7)
__device__ __forceinline__ float fast_gelu(float v) {
  float x = fabsf(v) * 0.70710678118654752f;
  float t = __builtin_amdgcn_rcpf(fmaf(0.3275911f, x, 1.0f));
  float s = fmaf(1.061405429f, t, -1.453152027f);
  s = fmaf(s, t, 1.421413741f);
  s = fmaf(s, t, -0.284496736f);
  s = fmaf(s, t, 0.254829592f);
  s = s * t;
  float e = __expf(-x * x);
  float erfa = fmaf(-s, e, 1.0f);          // erf(|x|)
  float erfs = copysignf(erfa, v);
  float hv = 0.5f * v;
  return fmaf(hv, erfs, hv);
}

// ---------------------------------------------------------------------------
// k_prep: all 4 weight fake-quants + rel-pos table pack, one launch.
// ---------------------------------------------------------------------------
__global__ __launch_bounds__(256) void k_prep(const float* __restrict__ qkvw,
    const float* __restrict__ projw, const float* __restrict__ lin1w,
    const float* __restrict__ lin2w, i8* __restrict__ wqb,
    const float* __restrict__ rph, const float* __restrict__ rpw,
    short* __restrict__ TB, const float* __restrict__ wsc) {
  int b = blockIdx.x;
  if (b < 1728) {
    int i = b * 256 + threadIdx.x;          // < 442368
    const float* w; int base, sidx;
    if (i < 110592)      { w = qkvw;  base = 0;      sidx = 0; }
    else if (i < 147456) { w = projw; base = 110592; sidx = 1; }
    else if (i < 294912) { w = lin1w; base = 147456; sidx = 2; }
    else                 { w = lin2w; base = 294912; sidx = 3; }
    float inv = 1.0f / wsc[sidx];
    const float4* src = (const float4*)w + (size_t)(i - base) * 4;
    i8 buf[16];
#pragma unroll
    for (int t = 0; t < 4; t++) {
      float4 f = src[t];
      buf[t*4+0] = satq(f.x * inv); buf[t*4+1] = satq(f.y * inv);
      buf[t*4+2] = satq(f.z * inv); buf[t*4+3] = satq(f.w * inv);
    }
    *(v4i*)(wqb + (size_t)i * 16) = *(v4i*)buf;
  } else {
    int g = (b - 1728) * 256 + threadIdx.x;  // < 1024
    int lane = g & 63, c = g >> 6;
    int p = c & 1, ks = (c >> 1) & 1, nt = (c >> 2) & 1, tb = c >> 3;
    const float* src = tb ? rpw : rph;
    int n = nt * 16 + (lane & 15);
    int k0 = ks * 32 + (lane >> 4) * 8;
    short outv[8];
#pragma unroll
    for (int j = 0; j < 8; j++) {
      float v = (n < 27) ? src[n * 64 + k0 + j] : 0.f;
      unsigned u = __float_as_uint(v);
      unsigned hi = (u + 0x7fffu + ((u >> 16) & 1u)) >> 16;
      if (p == 0) outv[j] = (short)hi;
      else {
        float lof = v - __uint_as_float(hi << 16);
        unsigned ul = __float_as_uint(lof);
        outv[j] = (short)((ul + 0x7fffu + ((ul >> 16) & 1u)) >> 16);
      }
    }
    *(v8s*)(TB + (size_t)c * 512 + lane * 8) = *(v8s*)outv;
  }
}

// ---------------------------------------------------------------------------
// LN1: wave per window-token (pad 64->70, 5x5 windows of 14x14), quant a_s[4]
// ---------------------------------------------------------------------------
__global__ __launch_bounds__(256) void k_ln1(const float* __restrict__ x,
    const float* __restrict__ w, const float* __restrict__ b,
    const float* __restrict__ as, i8* __restrict__ outq) {
  int wt = blockIdx.x * 4 + (threadIdx.x >> 6);
  int lane = threadIdx.x & 63;
  int win = wt / 196, tok = wt - win * 196;
  int bb = win / 25, wrem = win - bb * 25, wh = wrem / 5, ww = wrem - wh * 5;
  int r = tok / 14, c = tok - r * 14;
  int y = wh * 14 + r, xx = ww * 14 + c;
  i8* dst = outq + (size_t)wt * 768 + lane * 12;
  if (y >= 64 || xx >= 64) {
    ((int*)dst)[0] = 0; ((int*)dst)[1] = 0; ((int*)dst)[2] = 0;
    return;
  }
  const float* row = x + (((size_t)bb * 64 + y) * 64 + xx) * 768 + lane * 12;
  float v[12];
  *(float4*)(v)     = *(const float4*)(row);
  *(float4*)(v + 4) = *(const float4*)(row + 4);
  *(float4*)(v + 8) = *(const float4*)(row + 8);
  float s = 0.f, ss = 0.f;
#pragma unroll
  for (int j = 0; j < 12; j++) { s += v[j]; ss += v[j] * v[j]; }
#pragma unroll
  for (int off = 1; off < 64; off <<= 1) { s += __shfl_xor(s, off); ss += __shfl_xor(ss, off); }
  float mu = s * (1.0f / 768.0f);
  float var = ss * (1.0f / 768.0f) - mu * mu;
  float rstd = 1.0f / sqrtf(var + 1e-6f);
  float inv = 1.0f / as[4];
  float wv[12], bv[12];
  *(float4*)(wv)     = *(const float4*)(w + lane * 12);
  *(float4*)(wv + 4) = *(const float4*)(w + lane * 12 + 4);
  *(float4*)(wv + 8) = *(const float4*)(w + lane * 12 + 8);
  *(float4*)(bv)     = *(const float4*)(b + lane * 12);
  *(float4*)(bv + 4) = *(const float4*)(b + lane * 12 + 4);
  *(float4*)(bv + 8) = *(const float4*)(b + lane * 12 + 8);
  i8 q[12];
#pragma unroll
  for (int j = 0; j < 12; j++) q[j] = satq(((v[j] - mu) * rstd * wv[j] + bv[j]) * inv);
  ((int*)dst)[0] = pack4(q); ((int*)dst)[1] = pack4(q + 4); ((int*)dst)[2] = pack4(q + 8);
}

// ---------------------------------------------------------------------------
// LN2: wave per token, quant a_s[6]
// ---------------------------------------------------------------------------
__global__ __launch_bounds__(256) void k_ln2(const float* __restrict__ x2,
    const float* __restrict__ w, const float* __restrict__ b,
    const float* __restrict__ as, i8* __restrict__ outq) {
  int tokg = blockIdx.x * 4 + (threadIdx.x >> 6);
  int lane = threadIdx.x & 63;
  const float* row = x2 + (size_t)tokg * 768 + lane * 12;
  float v[12];
  *(float4*)(v)     = *(const float4*)(row);
  *(float4*)(v + 4) = *(const float4*)(row + 4);
  *(float4*)(v + 8) = *(const float4*)(row + 8);
  float s = 0.f, ss = 0.f;
#pragma unroll
  for (int j = 0; j < 12; j++) { s += v[j]; ss += v[j] * v[j]; }
#pragma unroll
  for (int off = 1; off < 64; off <<= 1) { s += __shfl_xor(s, off); ss += __shfl_xor(ss, off); }
  float mu = s * (1.0f / 768.0f);
  float var = ss * (1.0f / 768.0f) - mu * mu;
  float rstd = 1.0f / sqrtf(var + 1e-6f);
  float inv = 1.0f / as[6];
  float wv[12], bv[12];
  *(float4*)(wv)     = *(const float4*)(w + lane * 12);
  *(float4*)(wv + 4) = *(const float4*)(w + lane * 12 + 4);
  *(float4*)(wv + 8) = *(const float4*)(w + lane * 12 + 8);
  *(float4*)(bv)     = *(const float4*)(b + lane * 12);
  *(float4*)(bv + 4) = *(const float4*)(b + lane * 12 + 4);
  *(float4*)(bv + 8) = *(const float4*)(b + lane * 12 + 8);
  i8* dst = outq + (size_t)tokg * 768 + lane * 12;
  i8 q[12];
#pragma unroll
  for (int j = 0; j < 12; j++) q[j] = satq(((v[j] - mu) * rstd * wv[j] + bv[j]) * inv);
  ((int*)dst)[0] = pack4(q); ((int*)dst)[1] = pack4(q + 4); ((int*)dst)[2] = pack4(q + 8);
}

// ---------------------------------------------------------------------------
// int8 GEMM: C[M,N] = A[M,K] x B[N,K]^T, 128x128 tile, BK=64.  [R3 version]
// depth-2 pipeline, 3 LDS buffers, counted vmcnt, raw barriers, chunk-XOR
// swizzle, operand-swapped MFMA. N%128==0, K%64==0, K>=128.
// AHEAD: A is stored head-major: A[m][k] at ((win*12+k/64)*196+tok)*64+(k%64),
// win=m/196, tok=m%196 (K=768). Base/stride change only.
// Epi::store4(a, m, n0): a[r] = C[m][n0+r], n0%4==0, m<M guaranteed.
// ---------------------------------------------------------------------------
template <class Epi, bool AHEAD = false>
__global__ __launch_bounds__(256) void k_gemm(const i8* __restrict__ A, const i8* __restrict__ B,
                                              int M, int N, int K, Epi epi) {
  __shared__ __align__(16) i8 As[3][8192];
  __shared__ __align__(16) i8 Bs[3][8192];
  const int tid = threadIdx.x;
  const int lane = tid & 63, wave = tid >> 6;
  const int quad = lane >> 4, lc = lane & 15;
  const int wr = wave >> 1, wc = wave & 1;
  const long bm = (long)blockIdx.y * 128, bn = (long)blockIdx.x * 128;
  const v4i vz = {0, 0, 0, 0};
  v4i acc[4][4];
#pragma unroll
  for (int i = 0; i < 4; i++)
#pragma unroll
    for (int j = 0; j < 4; j++) acc[i][j] = vz;

  const int r0 = tid >> 2, c0 = tid & 3;
  const int cs = c0 ^ ((r0 >> 1) & 3);
  long rA0 = bm + r0;      if (rA0 >= M) rA0 = 0;
  long rA1 = bm + r0 + 64; if (rA1 >= M) rA1 = 0;
  const i8 *pA0, *pA1;
  long astep;
  if (AHEAD) {                       // head-major A (cs*16 < 64: head 0 start)
    long w0 = rA0 / 196, t0 = rA0 - w0 * 196;
    long w1 = rA1 / 196, t1 = rA1 - w1 * 196;
    pA0 = A + (w0 * 2352 + t0) * 64 + cs * 16;   // 12*196 = 2352
    pA1 = A + (w1 * 2352 + t1) * 64 + cs * 16;
    astep = 196 * 64;                // +1 head per 64-col K-step
  } else {
    pA0 = A + rA0 * (size_t)K + cs * 16;
    pA1 = A + rA1 * (size_t)K + cs * 16;
    astep = 64;
  }
  const i8* pB0 = B + (bn + r0)      * (size_t)K + cs * 16;
  const i8* pB1 = B + (bn + r0 + 64) * (size_t)K + cs * 16;

  auto stage = [&](int buf) {
    gload16(pA0, As[buf] + tid * 16); gload16(pA1, As[buf] + 4096 + tid * 16);
    gload16(pB0, Bs[buf] + tid * 16); gload16(pB1, Bs[buf] + 4096 + tid * 16);
    pA0 += astep; pA1 += astep; pB0 += 64; pB1 += 64;
  };

  const int xq16 = (quad ^ ((lc >> 1) & 3)) * 16;

  auto compute = [&](int buf) {
    v4i af[4], bf[4];
#pragma unroll
    for (int i = 0; i < 4; i++) af[i] = *(const v4i*)(As[buf] + (wr * 64 + i * 16 + lc) * 64 + xq16);
#pragma unroll
    for (int j = 0; j < 4; j++) bf[j] = *(const v4i*)(Bs[buf] + (wc * 64 + j * 16 + lc) * 64 + xq16);
#pragma unroll
    for (int i = 0; i < 4; i++)
#pragma unroll
      for (int j = 0; j < 4; j++)   // swapped operands: acc row ~ N, col ~ M
        acc[i][j] = __builtin_amdgcn_mfma_i32_16x16x64_i8(bf[j], af[i], acc[i][j], 0, 0, 0);
  };

  const int nt = K >> 6;
  stage(0); stage(1);               // tiles 0,1 in flight (8 loads/wave)
  int cb = 0, sb = 2;
  for (int t = 0; t < nt - 1; ++t) {
    asm volatile("s_waitcnt vmcnt(4)" ::: "memory");
    __builtin_amdgcn_s_barrier();
    asm volatile("" ::: "memory");
    if (t + 2 < nt) { stage(sb); if (++sb == 3) sb = 0; }
    compute(cb); if (++cb == 3) cb = 0;
  }
  asm volatile("s_waitcnt vmcnt(0)" ::: "memory");
  __builtin_amdgcn_s_barrier();
  asm volatile("" ::: "memory");
  compute(cb);

  Epi e = epi;
  e.init();
#pragma unroll
  for (int i = 0; i < 4; i++) {
    int gm = (int)bm + wr * 64 + i * 16 + lc;          // M row
#pragma unroll
    for (int j = 0; j < 4; j++) {
      int gn0 = (int)bn + wc * 64 + j * 16 + quad * 4; // N col (4 consecutive)
      if (gm < M) e.store4(acc[i][j], gm, gn0);
    }
  }
}

// -------- epilogues: store4(a, m, n0) with a[r] = C[m][n0+r], n0%4==0 ----
struct EpiQKV {   // split into q,k (token-major) and v^T (ch-major, stride 256)
  const float* as; const float* wsc; const float* bias;
  i8 *qq, *kq, *vt;
  float sab, invq, invk, invv;
  __device__ void init() {
    sab = as[4] * wsc[0]; invq = 1.f / as[0]; invk = 1.f / as[1]; invv = 1.f / as[2];
  }
  __device__ void store4(const v4i a, int m, int n0) {
    int t = n0 / 768, rem = n0 - t * 768;
    int head = rem >> 6, ch0 = rem & 63;              // ch0%4==0: same head for all 4
    int win = m / 196, tok = m - win * 196;
    size_t bh = (size_t)win * 12 + head;
    float4 bv = *(const float4*)(bias + n0);
    const float* bp = (const float*)&bv;
    if (t == 2) {
#pragma unroll
      for (int r = 0; r < 4; r++)
        vt[(bh * 64 + ch0 + r) * 256 + tok] = satq(((float)a[r] * sab + bp[r]) * invv);
    } else {
      float inv = (t == 0) ? invq : invk;
      i8 q[4];
#pragma unroll
      for (int r = 0; r < 4; r++) q[r] = satq(((float)a[r] * sab + bp[r]) * inv);
      *(int*)((t == 0 ? qq : kq) + (bh * 196 + tok) * 64 + ch0) = pack4(q);
    }
  }
};

struct EpiProj {  // window reverse + unpad + shortcut add -> x2 (in d_out)
  const float* as; const float* wsc; const float* bias; const float* x0; float* out;
  float sab;
  __device__ void init() { sab = as[5] * wsc[1]; }
  __device__ void store4(const v4i a, int m, int n0) {
    int win = m / 196, tok = m - win * 196;
    int bb = win / 25, wrem = win - bb * 25, wh = wrem / 5, ww = wrem - wh * 5;
    int rr = tok / 14, cc = tok - rr * 14;
    int y = wh * 14 + rr, xx = ww * 14 + cc;
    if (y >= 64 || xx >= 64) return;
    size_t o = (((size_t)bb * 64 + y) * 64 + xx) * 768 + n0;
    float4 bv = *(const float4*)(bias + n0);
    float4 xv = *(const float4*)(x0 + o);
    float4 ov;
    ov.x = (float)a[0] * sab + bv.x + xv.x;
    ov.y = (float)a[1] * sab + bv.y + xv.y;
    ov.z = (float)a[2] * sab + bv.z + xv.z;
    ov.w = (float)a[3] * sab + bv.w + xv.w;
    *(float4*)(out + o) = ov;
  }
};

struct EpiLin1 {  // bias + branch-free gelu + quant a_s[7]
  const float* as; const float* wsc; const float* bias; i8* outq;
  float sab, invg;
  __device__ void init() { sab = as[6] * wsc[2]; invg = 1.f / as[7]; }
  __device__ void store4(const v4i a, int m, int n0) {
    float4 bv = *(const float4*)(bias + n0);
    const float* bp = (const float*)&bv;
    i8 q[4];
#pragma unroll
    for (int r = 0; r < 4; r++) {
      float v = fmaf((float)a[r], sab, bp[r]);
      q[r] = satq(fast_gelu(v) * invg);
    }
    *(int*)(outq + (size_t)m * 3072 + n0) = pack4(q);
  }
};

struct EpiLin2 {  // bias + residual add into d_out
  const float* as; const float* wsc; const float* bias; float* out;
  float sab;
  __device__ void init() { sab = as[7] * wsc[3]; }
  __device__ void store4(const v4i a, int m, int n0) {
    size_t o = (size_t)m * 768 + n0;
    float4 bv = *(const float4*)(bias + n0);
    float4 ov = *(const float4*)(out + o);
    ov.x += (float)a[0] * sab + bv.x;
    ov.y += (float)a[1] * sab + bv.y;
    ov.z += (float)a[2] * sab + bv.z;
    ov.w += (float)a[3] * sab + bv.w;
    *(float4*)(out + o) = ov;
  }
};

// ---------------------------------------------------------------------------
// attention: ONE WAVE per (bh, 16-row tile). Grid 15600 x 64 thr, with
// XCD-colocating bijective remap (15600 = 8*1950). Swapped QK^T (register P);
// swapped PV; O quad<->nt transposed in-register -> one dwordx4 store/lane
// into head-major attno [bh][tok][64] (full 64B lines, written once).
// ---------------------------------------------------------------------------
__global__ __launch_bounds__(64, 4) void k_attn(const i8* __restrict__ qq, const i8* __restrict__ kq,
    const i8* __restrict__ vt, const short* __restrict__ TB,
    const float* __restrict__ as, i8* __restrict__ outq) {
  __shared__ float relS[16][66];                  // rel bias [q-row][d(h)|32+d(w)]
  const int g = blockIdx.x;
  const int work = (g & 7) * 1950 + (g >> 3);    // bijective: 15600 = 8*1950
  const int bh = work / 13;
  const int t = work - bh * 13;
  const int win = bh / 12;
  const int lane = threadIdx.x;
  const int quad = lane >> 4, lc = lane & 15;
  const float s0 = as[0];
  const float ssc = s0 * as[1] * 0.125f;
  const float invs3 = 1.0f / as[3];
  const float oscale = as[2] * as[3] / as[5];

  const v8s* TBv = (const v8s*)TB;
  const v4i vz = {0, 0, 0, 0};

  // ---- rel-pos bias via bf16 MFMA (writes relS[row=quad*4+r][...]) ----
  {
    int arow = t * 16 + lc; if (arow > 195) arow = 195;
    const i8* qrow = qq + ((size_t)bh * 196 + arow) * 64;
    v8s af[2];
#pragma unroll
    for (int ks = 0; ks < 2; ks++) {
      const i8* p = qrow + ks * 32 + quad * 8;
#pragma unroll
      for (int j = 0; j < 8; j++)
        af[ks][j] = (short)(__float_as_uint((float)p[j]) >> 16);  // exact int->bf16
    }
    v4f rh0 = {0,0,0,0}, rh1 = {0,0,0,0}, rw0 = {0,0,0,0}, rw1 = {0,0,0,0};
#pragma unroll
    for (int ks = 0; ks < 2; ks++)
#pragma unroll
      for (int p2 = 0; p2 < 2; p2++) {
        rh0 = __builtin_amdgcn_mfma_f32_16x16x32_bf16(af[ks], TBv[(0*4 + ks*2 + p2)*64 + lane], rh0, 0, 0, 0);
        rh1 = __builtin_amdgcn_mfma_f32_16x16x32_bf16(af[ks], TBv[(1*4 + ks*2 + p2)*64 + lane], rh1, 0, 0, 0);
        rw0 = __builtin_amdgcn_mfma_f32_16x16x32_bf16(af[ks], TBv[(2*4 + ks*2 + p2)*64 + lane], rw0, 0, 0, 0);
        rw1 = __builtin_amdgcn_mfma_f32_16x16x32_bf16(af[ks], TBv[(3*4 + ks*2 + p2)*64 + lane], rw1, 0, 0, 0);
      }
#pragma unroll
    for (int r = 0; r < 4; r++) {
      int rl = quad * 4 + r;
      relS[rl][lc]      = rh0[r] * s0;
      relS[rl][16 + lc] = rh1[r] * s0;
      relS[rl][32 + lc] = rw0[r] * s0;
      relS[rl][48 + lc] = rw1[r] * s0;
    }
  }

  // ---- QK^T, SWAPPED (int-exact): lane (quad,lc) holds P-row q=lc at
  // k = f*16+quad*4+r ----
  v4i aq = *(const v4i*)(qq + ((size_t)bh * 196 + t * 16 + lc) * 64 + quad * 16);
  v4i sacc[13];
#pragma unroll
  for (int f = 0; f < 13; f++) {
    v4i bk = *(const v4i*)(kq + ((size_t)bh * 196 + f * 16 + lc) * 64 + quad * 16);
    sacc[f] = __builtin_amdgcn_mfma_i32_16x16x64_i8(bk, aq, vz, 0, 0, 0);
  }

  // per-reg (kh<<4|kw) nibble table: compile-time constants selected by quad
  unsigned khw[13];
#pragma unroll
  for (int f = 0; f < 13; f++) {
    unsigned w0 = 0, w1 = 0, w2 = 0, w3 = 0;
#pragma unroll
    for (int r = 0; r < 4; r++) {
      int k0 = f*16 + 0*4 + r; if (k0 > 195) k0 = 195;
      int k1 = f*16 + 1*4 + r; if (k1 > 195) k1 = 195;
      int k2 = f*16 + 2*4 + r; if (k2 > 195) k2 = 195;
      int k3 = f*16 + 3*4 + r; if (k3 > 195) k3 = 195;
      w0 |= (unsigned)(((k0/14) << 4) | (k0 - (k0/14)*14)) << (r*8);
      w1 |= (unsigned)(((k1/14) << 4) | (k1 - (k1/14)*14)) << (r*8);
      w2 |= (unsigned)(((k2/14) << 4) | (k2 - (k2/14)*14)) << (r*8);
      w3 |= (unsigned)(((k3/14) << 4) | (k3 - (k3/14)*14)) << (r*8);
    }
    khw[f] = quad == 0 ? w0 : quad == 1 ? w1 : quad == 2 ? w2 : w3;
  }

  // ---- softmax (per-lane row q = lc) ----
  int qrow = t * 16 + lc;                       // >=196 only for t=12: junk, store-guarded
  int qh = qrow / 14, qw = qrow - qh * 14;
  const float* rH = &relS[lc][13 + qh];         // rH[-kh]
  const float* rW = &relS[lc][32 + 13 + qw];    // rW[-kw]
  float L[13][4];
  float mx = -1e30f;
#pragma unroll
  for (int f = 0; f < 13; f++)
#pragma unroll
    for (int r = 0; r < 4; r++) {
      int kh = (int)((khw[f] >> (r * 8 + 4)) & 0xfu);
      int kw = (int)((khw[f] >> (r * 8)) & 0xfu);
      float v = ((f < 12) | (quad == 0))
                  ? fmaf((float)sacc[f][r], ssc, rH[-kh] + rW[-kw]) : -1e30f;
      L[f][r] = v;
      mx = fmaxf(mx, v);
    }
  mx = fmaxf(mx, __shfl_xor(mx, 16));
  mx = fmaxf(mx, __shfl_xor(mx, 32));
  float sum = 0.f;
#pragma unroll
  for (int f = 0; f < 13; f++)
#pragma unroll
    for (int r = 0; r < 4; r++) { float e = __expf(L[f][r] - mx); L[f][r] = e; sum += e; }
  sum += __shfl_xor(sum, 16);
  sum += __shfl_xor(sum, 32);
  float cq = (1.0f / sum) * invs3;

  // quantize P to packed words: W[f] = P[q=lc][f*16+quad*4 .. +4]
  unsigned W[16];
#pragma unroll
  for (int f = 0; f < 13; f++) {
    i8 q4[4];
#pragma unroll
    for (int r = 0; r < 4; r++) q4[r] = satq(L[f][r] * cq);
    W[f] = (unsigned)pack4(q4);
  }
  W[13] = 0; W[14] = 0; W[15] = 0;

  const bool q0m = (quad & 1) == 0, q1m = (quad & 2) == 0;

  // ---- PV (int-exact), A-frags via in-register 4x4 quad-word transpose ----
  v4i oacc[4];
#pragma unroll
  for (int nt = 0; nt < 4; nt++) oacc[nt] = vz;
#pragma unroll
  for (int kc = 0; kc < 4; kc++) {
    unsigned a0 = W[kc*4+0], a1 = W[kc*4+1], a2 = W[kc*4+2], a3 = W[kc*4+3];
    unsigned s0_ = (unsigned)__shfl_xor((int)a1, 16);
    unsigned s1_ = (unsigned)__shfl_xor((int)a0, 16);
    unsigned s2_ = (unsigned)__shfl_xor((int)a3, 16);
    unsigned s3_ = (unsigned)__shfl_xor((int)a2, 16);
    unsigned x0 = q0m ? a0 : s0_;
    unsigned x1 = q0m ? s1_ : a1;
    unsigned x2 = q0m ? a2 : s2_;
    unsigned x3 = q0m ? s3_ : a3;
    unsigned u0 = (unsigned)__shfl_xor((int)x2, 32);
    unsigned u1 = (unsigned)__shfl_xor((int)x3, 32);
    unsigned u2 = (unsigned)__shfl_xor((int)x0, 32);
    unsigned u3 = (unsigned)__shfl_xor((int)x1, 32);
    v4i ap;
    ap[0] = (int)(q1m ? x0 : u0);
    ap[1] = (int)(q1m ? x1 : u1);
    ap[2] = (int)(q1m ? u2 : x2);
    ap[3] = (int)(q1m ? u3 : x3);
#pragma unroll
    for (int nt = 0; nt < 4; nt++) {
      v4i bv = *(const v4i*)(vt + ((size_t)bh * 64 + nt * 16 + lc) * 256 + kc * 64 + quad * 16);
      // SWAPPED: lane holds O[q=lc][ch=nt*16+quad*4+r]
      oacc[nt] = __builtin_amdgcn_mfma_i32_16x16x64_i8(bv, ap, oacc[nt], 0, 0, 0);
    }
  }

  // quantize O to words: W2[nt] = O[q=lc] dwords (ch/4 = nt*4+quad)
  unsigned W2[4];
#pragma unroll
  for (int nt = 0; nt < 4; nt++) {
    i8 q4[4];
#pragma unroll
    for (int r = 0; r < 4; r++) q4[r] = satq((float)oacc[nt][r] * oscale);
    W2[nt] = (unsigned)pack4(q4);
  }
  // transpose quad<->nt (same butterfly) -> lane holds dwords quad*4..+3 of
  // its row -> ONE dwordx4 store: full 64B line per 4 lanes, contiguous 1KB.
  {
    unsigned a0 = W2[0], a1 = W2[1], a2 = W2[2], a3 = W2[3];
    unsigned s0_ = (unsigned)__shfl_xor((int)a1, 16);
    unsigned s1_ = (unsigned)__shfl_xor((int)a0, 16);
    unsigned s2_ = (unsigned)__shfl_xor((int)a3, 16);
    unsigned s3_ = (unsigned)__shfl_xor((int)a2, 16);
    unsigned x0 = q0m ? a0 : s0_;
    unsigned x1 = q0m ? s1_ : a1;
    unsigned x2 = q0m ? a2 : s2_;
    unsigned x3 = q0m ? s3_ : a3;
    unsigned u0 = (unsigned)__shfl_xor((int)x2, 32);
    unsigned u1 = (unsigned)__shfl_xor((int)x3, 32);
    unsigned u2 = (unsigned)__shfl_xor((int)x0, 32);
    unsigned u3 = (unsigned)__shfl_xor((int)x1, 32);
    v4i ot;
    ot[0] = (int)(q1m ? x0 : u0);
    ot[1] = (int)(q1m ? x1 : u1);
    ot[2] = (int)(q1m ? u2 : x2);
    ot[3] = (int)(q1m ? u3 : x3);
    // ot dword d = O[q=lc][ (quad*4+d)*4 .. +4 ] -> bytes quad*16 .. of row
    if (t * 16 + lc < 196)
      *(v4i*)(outq + ((size_t)bh * 196 + t * 16 + lc) * 64 + quad * 16) = ot;
  }
}

// ---------------------------------------------------------------------------
extern "C" void kernel_launch(void* const* d_in, const int* in_sizes, int n_in,
                              void* d_out, int out_size, void* d_ws, size_t ws_size,
                              hipStream_t stream) {
  const float* x     = (const float*)d_in[0];
  const float* ln1w  = (const float*)d_in[1];
  const float* ln1b  = (const float*)d_in[2];
  const float* ln2w  = (const float*)d_in[3];
  const float* ln2b  = (const float*)d_in[4];
  const float* qkvw  = (const float*)d_in[5];
  const float* qkvb  = (const float*)d_in[6];
  const float* projw = (const float*)d_in[7];
  const float* projb = (const float*)d_in[8];
  const float* lin1w = (const float*)d_in[9];
  const float* lin1b = (const float*)d_in[10];
  const float* lin2w = (const float*)d_in[11];
  const float* lin2b = (const float*)d_in[12];
  const float* rph   = (const float*)d_in[13];
  const float* rpw   = (const float*)d_in[14];
  const float* as    = (const float*)d_in[15];
  const float* wsc   = (const float*)d_in[16];
  float* out = (float*)d_out;

  // ws layout (72,462,336 B total), regions reused across stages:
  char* ws = (char*)d_ws;
  i8* big    = (i8*)ws;                          // 50,331,648
  i8* qq     = big;                              // 15,052,800 (1200*196*64)
  i8* kq     = big + 15052800;                   // 15,052,800
  i8* vt     = big + 30105600;                   // 19,660,800 (1200*64*256)
  short* TB  = (short*)(big + 49766400);         //     16,384 (rel tables; dead before lin1)
  i8* mlpq   = big;                              // 50,331,648 (16384*3072), after attn
  i8* creg   = (i8*)(ws + 50331648);             // 15,052,800
  i8* winq   = creg;                             // qkv input
  i8* attno  = creg;                             // proj input, head-major [bh][tok][64]
  i8* yq     = creg;                             // lin1 input (after proj dead)
  i8* wqb    = (i8*)(ws + 65384448);             //  7,077,888 (all 4 wq, contiguous)
  i8* qkvwq  = wqb;
  i8* projwq = wqb + 1769472;
  i8* lin1wq = projwq + 589824;
  i8* lin2wq = lin1wq + 2359296;

  k_prep<<<1732, 256, 0, stream>>>(qkvw, projw, lin1w, lin2w, wqb, rph, rpw, TB, wsc);

  k_ln1<<<4900, 256, 0, stream>>>(x, ln1w, ln1b, as, winq);

  { EpiQKV e{as, wsc, qkvb, qq, kq, vt};
    k_gemm<EpiQKV><<<dim3(18, 154), 256, 0, stream>>>(winq, qkvwq, 19600, 2304, 768, e); }

  k_attn<<<15600, 64, 0, stream>>>(qq, kq, vt, TB, as, attno);

  { EpiProj e{as, wsc, projb, x, out};
    k_gemm<EpiProj, true><<<dim3(6, 154), 256, 0, stream>>>(attno, projwq, 19600, 768, 768, e); }

  k_ln2<<<4096, 256, 0, stream>>>(out, ln2w, ln2b, as, yq);

  { EpiLin1 e{as, wsc, lin1b, mlpq};
    k_gemm<EpiLin1><<<dim3(24, 128), 256, 0, stream>>>(yq, lin1wq, 16384, 3072, 768, e); }

  { EpiLin2 e{as, wsc, lin2b, out};
    k_gemm<EpiLin2><<<dim3(6, 128), 256, 0, stream>>>(mlpq, lin2wq, 16384, 768, 3072, e); }
}

// Round 8
// 466.679 us; speedup vs baseline: 1.1162x; 1.0913x over previous
//
#include <hip/hip_runtime.h>
#include <cstdint>

// ============================================================================
// QunatEncoderBlock: windowed attention block with int8 fake-quant.
// All qlinear / QK^T / PV matmuls are EXACT in int8xint8->int32 (MFMA i8).
// Rel-pos bias via bf16 MFMA with hi/lo split tables (error ~2^-18).
// R1: k_attn 1-wave/1-tile blocks. R2: branch-free erf gelu (lin1 99->89).
// R3: gemm chunk-XOR swizzle (conflicts 4.7M->0) + depth-2 vmcnt pipeline.
// R4: 8-phase 256^2 port regressed (1 block/CU) -> reverted to R3 gemm.
// R5: k_attn swapped-QK^T register-resident P; k_prep fusion.
// R6: XCD-colocating remap: FETCH 200->80MB. R7: full-line dwordx4 O stores.
//     WRITE stuck at 131MB across ALL layouts -> NOT output traffic.
// R8: ROOT CAUSE of the 131MB: __launch_bounds__(64,4) capped the allocator
//     at 128 VGPR and it pinned 64 -> ~70 regs of sacc/L/W spilled to
//     SCRATCH (= HBM): ~110MB spill writes + reloads, layout-invariant.
//     (R0-R4's 256-thr kernel at VGPR=140 wrote exactly the 15MB ideal.)
//     Fix: __launch_bounds__(64) -> allocator takes ~150 VGPR, zero spill.
//     Occupancy drops (fine: kernel is HBM-traffic-bound; traffic falls
//     217MB -> ~75MB logical floor).
// ============================================================================

typedef int   v4i __attribute__((ext_vector_type(4)));
typedef float v4f __attribute__((ext_vector_type(4)));
typedef short v8s __attribute__((ext_vector_type(8)));
typedef int8_t i8;

__device__ __forceinline__ i8 satq(float x) {   // x already scale-divided
  float q = rintf(x);
  q = fminf(127.f, fmaxf(-128.f, q));
  return (i8)(int)q;
}

__device__ __forceinline__ void gload16(const i8* g, i8* l) {
  __builtin_amdgcn_global_load_lds((const __attribute__((address_space(1))) void*)g,
                                   (__attribute__((address_space(3))) void*)l, 16, 0, 0);
}

__device__ __forceinline__ int pack4(const i8* q) {
  return ((int)(unsigned char)q[0]) | ((int)(unsigned char)q[1] << 8) |
         ((int)(unsigned char)q[2] << 16) | ((int)(unsigned char)q[3] << 24);
}

// branch-free gelu: 0.5*v*(1+erf(v/sqrt2)), erf via A-S 7.1.26 (|err|<=1.5e-7)
__device__ __forceinline__ float fast_gelu(float v) {
  float x = fabsf(v) * 0.70710678118654752f;
  float t = __builtin_amdgcn_rcpf(fmaf(0.3275911f, x, 1.0f));
  float s = fmaf(1.061405429f, t, -1.453152027f);
  s = fmaf(s, t, 1.421413741f);
  s = fmaf(s, t, -0.284496736f);
  s = fmaf(s, t, 0.254829592f);
  s = s * t;
  float e = __expf(-x * x);
  float erfa = fmaf(-s, e, 1.0f);          // erf(|x|)
  float erfs = copysignf(erfa, v);
  float hv = 0.5f * v;
  return fmaf(hv, erfs, hv);
}

// ---------------------------------------------------------------------------
// k_prep: all 4 weight fake-quants + rel-pos table pack, one launch.
// ---------------------------------------------------------------------------
__global__ __launch_bounds__(256) void k_prep(const float* __restrict__ qkvw,
    const float* __restrict__ projw, const float* __restrict__ lin1w,
    const float* __restrict__ lin2w, i8* __restrict__ wqb,
    const float* __restrict__ rph, const float* __restrict__ rpw,
    short* __restrict__ TB, const float* __restrict__ wsc) {
  int b = blockIdx.x;
  if (b < 1728) {
    int i = b * 256 + threadIdx.x;          // < 442368
    const float* w; int base, sidx;
    if (i < 110592)      { w = qkvw;  base = 0;      sidx = 0; }
    else if (i < 147456) { w = projw; base = 110592; sidx = 1; }
    else if (i < 294912) { w = lin1w; base = 147456; sidx = 2; }
    else                 { w = lin2w; base = 294912; sidx = 3; }
    float inv = 1.0f / wsc[sidx];
    const float4* src = (const float4*)w + (size_t)(i - base) * 4;
    i8 buf[16];
#pragma unroll
    for (int t = 0; t < 4; t++) {
      float4 f = src[t];
      buf[t*4+0] = satq(f.x * inv); buf[t*4+1] = satq(f.y * inv);
      buf[t*4+2] = satq(f.z * inv); buf[t*4+3] = satq(f.w * inv);
    }
    *(v4i*)(wqb + (size_t)i * 16) = *(v4i*)buf;
  } else {
    int g = (b - 1728) * 256 + threadIdx.x;  // < 1024
    int lane = g & 63, c = g >> 6;
    int p = c & 1, ks = (c >> 1) & 1, nt = (c >> 2) & 1, tb = c >> 3;
    const float* src = tb ? rpw : rph;
    int n = nt * 16 + (lane & 15);
    int k0 = ks * 32 + (lane >> 4) * 8;
    short outv[8];
#pragma unroll
    for (int j = 0; j < 8; j++) {
      float v = (n < 27) ? src[n * 64 + k0 + j] : 0.f;
      unsigned u = __float_as_uint(v);
      unsigned hi = (u + 0x7fffu + ((u >> 16) & 1u)) >> 16;
      if (p == 0) outv[j] = (short)hi;
      else {
        float lof = v - __uint_as_float(hi << 16);
        unsigned ul = __float_as_uint(lof);
        outv[j] = (short)((ul + 0x7fffu + ((ul >> 16) & 1u)) >> 16);
      }
    }
    *(v8s*)(TB + (size_t)c * 512 + lane * 8) = *(v8s*)outv;
  }
}

// ---------------------------------------------------------------------------
// LN1: wave per window-token (pad 64->70, 5x5 windows of 14x14), quant a_s[4]
// ---------------------------------------------------------------------------
__global__ __launch_bounds__(256) void k_ln1(const float* __restrict__ x,
    const float* __restrict__ w, const float* __restrict__ b,
    const float* __restrict__ as, i8* __restrict__ outq) {
  int wt = blockIdx.x * 4 + (threadIdx.x >> 6);
  int lane = threadIdx.x & 63;
  int win = wt / 196, tok = wt - win * 196;
  int bb = win / 25, wrem = win - bb * 25, wh = wrem / 5, ww = wrem - wh * 5;
  int r = tok / 14, c = tok - r * 14;
  int y = wh * 14 + r, xx = ww * 14 + c;
  i8* dst = outq + (size_t)wt * 768 + lane * 12;
  if (y >= 64 || xx >= 64) {
    ((int*)dst)[0] = 0; ((int*)dst)[1] = 0; ((int*)dst)[2] = 0;
    return;
  }
  const float* row = x + (((size_t)bb * 64 + y) * 64 + xx) * 768 + lane * 12;
  float v[12];
  *(float4*)(v)     = *(const float4*)(row);
  *(float4*)(v + 4) = *(const float4*)(row + 4);
  *(float4*)(v + 8) = *(const float4*)(row + 8);
  float s = 0.f, ss = 0.f;
#pragma unroll
  for (int j = 0; j < 12; j++) { s += v[j]; ss += v[j] * v[j]; }
#pragma unroll
  for (int off = 1; off < 64; off <<= 1) { s += __shfl_xor(s, off); ss += __shfl_xor(ss, off); }
  float mu = s * (1.0f / 768.0f);
  float var = ss * (1.0f / 768.0f) - mu * mu;
  float rstd = 1.0f / sqrtf(var + 1e-6f);
  float inv = 1.0f / as[4];
  float wv[12], bv[12];
  *(float4*)(wv)     = *(const float4*)(w + lane * 12);
  *(float4*)(wv + 4) = *(const float4*)(w + lane * 12 + 4);
  *(float4*)(wv + 8) = *(const float4*)(w + lane * 12 + 8);
  *(float4*)(bv)     = *(const float4*)(b + lane * 12);
  *(float4*)(bv + 4) = *(const float4*)(b + lane * 12 + 4);
  *(float4*)(bv + 8) = *(const float4*)(b + lane * 12 + 8);
  i8 q[12];
#pragma unroll
  for (int j = 0; j < 12; j++) q[j] = satq(((v[j] - mu) * rstd * wv[j] + bv[j]) * inv);
  ((int*)dst)[0] = pack4(q); ((int*)dst)[1] = pack4(q + 4); ((int*)dst)[2] = pack4(q + 8);
}

// ---------------------------------------------------------------------------
// LN2: wave per token, quant a_s[6]
// ---------------------------------------------------------------------------
__global__ __launch_bounds__(256) void k_ln2(const float* __restrict__ x2,
    const float* __restrict__ w, const float* __restrict__ b,
    const float* __restrict__ as, i8* __restrict__ outq) {
  int tokg = blockIdx.x * 4 + (threadIdx.x >> 6);
  int lane = threadIdx.x & 63;
  const float* row = x2 + (size_t)tokg * 768 + lane * 12;
  float v[12];
  *(float4*)(v)     = *(const float4*)(row);
  *(float4*)(v + 4) = *(const float4*)(row + 4);
  *(float4*)(v + 8) = *(const float4*)(row + 8);
  float s = 0.f, ss = 0.f;
#pragma unroll
  for (int j = 0; j < 12; j++) { s += v[j]; ss += v[j] * v[j]; }
#pragma unroll
  for (int off = 1; off < 64; off <<= 1) { s += __shfl_xor(s, off); ss += __shfl_xor(ss, off); }
  float mu = s * (1.0f / 768.0f);
  float var = ss * (1.0f / 768.0f) - mu * mu;
  float rstd = 1.0f / sqrtf(var + 1e-6f);
  float inv = 1.0f / as[6];
  float wv[12], bv[12];
  *(float4*)(wv)     = *(const float4*)(w + lane * 12);
  *(float4*)(wv + 4) = *(const float4*)(w + lane * 12 + 4);
  *(float4*)(wv + 8) = *(const float4*)(w + lane * 12 + 8);
  *(float4*)(bv)     = *(const float4*)(b + lane * 12);
  *(float4*)(bv + 4) = *(const float4*)(b + lane * 12 + 4);
  *(float4*)(bv + 8) = *(const float4*)(b + lane * 12 + 8);
  i8* dst = outq + (size_t)tokg * 768 + lane * 12;
  i8 q[12];
#pragma unroll
  for (int j = 0; j < 12; j++) q[j] = satq(((v[j] - mu) * rstd * wv[j] + bv[j]) * inv);
  ((int*)dst)[0] = pack4(q); ((int*)dst)[1] = pack4(q + 4); ((int*)dst)[2] = pack4(q + 8);
}

// ---------------------------------------------------------------------------
// int8 GEMM: C[M,N] = A[M,K] x B[N,K]^T, 128x128 tile, BK=64.  [R3 version]
// depth-2 pipeline, 3 LDS buffers, counted vmcnt, raw barriers, chunk-XOR
// swizzle, operand-swapped MFMA. N%128==0, K%64==0, K>=128.
// AHEAD: A is stored head-major: A[m][k] at ((win*12+k/64)*196+tok)*64+(k%64).
// Epi::store4(a, m, n0): a[r] = C[m][n0+r], n0%4==0, m<M guaranteed.
// ---------------------------------------------------------------------------
template <class Epi, bool AHEAD = false>
__global__ __launch_bounds__(256) void k_gemm(const i8* __restrict__ A, const i8* __restrict__ B,
                                              int M, int N, int K, Epi epi) {
  __shared__ __align__(16) i8 As[3][8192];
  __shared__ __align__(16) i8 Bs[3][8192];
  const int tid = threadIdx.x;
  const int lane = tid & 63, wave = tid >> 6;
  const int quad = lane >> 4, lc = lane & 15;
  const int wr = wave >> 1, wc = wave & 1;
  const long bm = (long)blockIdx.y * 128, bn = (long)blockIdx.x * 128;
  const v4i vz = {0, 0, 0, 0};
  v4i acc[4][4];
#pragma unroll
  for (int i = 0; i < 4; i++)
#pragma unroll
    for (int j = 0; j < 4; j++) acc[i][j] = vz;

  const int r0 = tid >> 2, c0 = tid & 3;
  const int cs = c0 ^ ((r0 >> 1) & 3);
  long rA0 = bm + r0;      if (rA0 >= M) rA0 = 0;
  long rA1 = bm + r0 + 64; if (rA1 >= M) rA1 = 0;
  const i8 *pA0, *pA1;
  long astep;
  if (AHEAD) {                       // head-major A (cs*16 < 64: head 0 start)
    long w0 = rA0 / 196, t0 = rA0 - w0 * 196;
    long w1 = rA1 / 196, t1 = rA1 - w1 * 196;
    pA0 = A + (w0 * 2352 + t0) * 64 + cs * 16;   // 12*196 = 2352
    pA1 = A + (w1 * 2352 + t1) * 64 + cs * 16;
    astep = 196 * 64;                // +1 head per 64-col K-step
  } else {
    pA0 = A + rA0 * (size_t)K + cs * 16;
    pA1 = A + rA1 * (size_t)K + cs * 16;
    astep = 64;
  }
  const i8* pB0 = B + (bn + r0)      * (size_t)K + cs * 16;
  const i8* pB1 = B + (bn + r0 + 64) * (size_t)K + cs * 16;

  auto stage = [&](int buf) {
    gload16(pA0, As[buf] + tid * 16); gload16(pA1, As[buf] + 4096 + tid * 16);
    gload16(pB0, Bs[buf] + tid * 16); gload16(pB1, Bs[buf] + 4096 + tid * 16);
    pA0 += astep; pA1 += astep; pB0 += 64; pB1 += 64;
  };

  const int xq16 = (quad ^ ((lc >> 1) & 3)) * 16;

  auto compute = [&](int buf) {
    v4i af[4], bf[4];
#pragma unroll
    for (int i = 0; i < 4; i++) af[i] = *(const v4i*)(As[buf] + (wr * 64 + i * 16 + lc) * 64 + xq16);
#pragma unroll
    for (int j = 0; j < 4; j++) bf[j] = *(const v4i*)(Bs[buf] + (wc * 64 + j * 16 + lc) * 64 + xq16);
#pragma unroll
    for (int i = 0; i < 4; i++)
#pragma unroll
      for (int j = 0; j < 4; j++)   // swapped operands: acc row ~ N, col ~ M
        acc[i][j] = __builtin_amdgcn_mfma_i32_16x16x64_i8(bf[j], af[i], acc[i][j], 0, 0, 0);
  };

  const int nt = K >> 6;
  stage(0); stage(1);               // tiles 0,1 in flight (8 loads/wave)
  int cb = 0, sb = 2;
  for (int t = 0; t < nt - 1; ++t) {
    asm volatile("s_waitcnt vmcnt(4)" ::: "memory");
    __builtin_amdgcn_s_barrier();
    asm volatile("" ::: "memory");
    if (t + 2 < nt) { stage(sb); if (++sb == 3) sb = 0; }
    compute(cb); if (++cb == 3) cb = 0;
  }
  asm volatile("s_waitcnt vmcnt(0)" ::: "memory");
  __builtin_amdgcn_s_barrier();
  asm volatile("" ::: "memory");
  compute(cb);

  Epi e = epi;
  e.init();
#pragma unroll
  for (int i = 0; i < 4; i++) {
    int gm = (int)bm + wr * 64 + i * 16 + lc;          // M row
#pragma unroll
    for (int j = 0; j < 4; j++) {
      int gn0 = (int)bn + wc * 64 + j * 16 + quad * 4; // N col (4 consecutive)
      if (gm < M) e.store4(acc[i][j], gm, gn0);
    }
  }
}

// -------- epilogues: store4(a, m, n0) with a[r] = C[m][n0+r], n0%4==0 ----
struct EpiQKV {   // split into q,k (token-major) and v^T (ch-major, stride 256)
  const float* as; const float* wsc; const float* bias;
  i8 *qq, *kq, *vt;
  float sab, invq, invk, invv;
  __device__ void init() {
    sab = as[4] * wsc[0]; invq = 1.f / as[0]; invk = 1.f / as[1]; invv = 1.f / as[2];
  }
  __device__ void store4(const v4i a, int m, int n0) {
    int t = n0 / 768, rem = n0 - t * 768;
    int head = rem >> 6, ch0 = rem & 63;              // ch0%4==0: same head for all 4
    int win = m / 196, tok = m - win * 196;
    size_t bh = (size_t)win * 12 + head;
    float4 bv = *(const float4*)(bias + n0);
    const float* bp = (const float*)&bv;
    if (t == 2) {
#pragma unroll
      for (int r = 0; r < 4; r++)
        vt[(bh * 64 + ch0 + r) * 256 + tok] = satq(((float)a[r] * sab + bp[r]) * invv);
    } else {
      float inv = (t == 0) ? invq : invk;
      i8 q[4];
#pragma unroll
      for (int r = 0; r < 4; r++) q[r] = satq(((float)a[r] * sab + bp[r]) * inv);
      *(int*)((t == 0 ? qq : kq) + (bh * 196 + tok) * 64 + ch0) = pack4(q);
    }
  }
};

struct EpiProj {  // window reverse + unpad + shortcut add -> x2 (in d_out)
  const float* as; const float* wsc; const float* bias; const float* x0; float* out;
  float sab;
  __device__ void init() { sab = as[5] * wsc[1]; }
  __device__ void store4(const v4i a, int m, int n0) {
    int win = m / 196, tok = m - win * 196;
    int bb = win / 25, wrem = win - bb * 25, wh = wrem / 5, ww = wrem - wh * 5;
    int rr = tok / 14, cc = tok - rr * 14;
    int y = wh * 14 + rr, xx = ww * 14 + cc;
    if (y >= 64 || xx >= 64) return;
    size_t o = (((size_t)bb * 64 + y) * 64 + xx) * 768 + n0;
    float4 bv = *(const float4*)(bias + n0);
    float4 xv = *(const float4*)(x0 + o);
    float4 ov;
    ov.x = (float)a[0] * sab + bv.x + xv.x;
    ov.y = (float)a[1] * sab + bv.y + xv.y;
    ov.z = (float)a[2] * sab + bv.z + xv.z;
    ov.w = (float)a[3] * sab + bv.w + xv.w;
    *(float4*)(out + o) = ov;
  }
};

struct EpiLin1 {  // bias + branch-free gelu + quant a_s[7]
  const float* as; const float* wsc; const float* bias; i8* outq;
  float sab, invg;
  __device__ void init() { sab = as[6] * wsc[2]; invg = 1.f / as[7]; }
  __device__ void store4(const v4i a, int m, int n0) {
    float4 bv = *(const float4*)(bias + n0);
    const float* bp = (const float*)&bv;
    i8 q[4];
#pragma unroll
    for (int r = 0; r < 4; r++) {
      float v = fmaf((float)a[r], sab, bp[r]);
      q[r] = satq(fast_gelu(v) * invg);
    }
    *(int*)(outq + (size_t)m * 3072 + n0) = pack4(q);
  }
};

struct EpiLin2 {  // bias + residual add into d_out
  const float* as; const float* wsc; const float* bias; float* out;
  float sab;
  __device__ void init() { sab = as[7] * wsc[3]; }
  __device__ void store4(const v4i a, int m, int n0) {
    size_t o = (size_t)m * 768 + n0;
    float4 bv = *(const float4*)(bias + n0);
    float4 ov = *(const float4*)(out + o);
    ov.x += (float)a[0] * sab + bv.x;
    ov.y += (float)a[1] * sab + bv.y;
    ov.z += (float)a[2] * sab + bv.z;
    ov.w += (float)a[3] * sab + bv.w;
    *(float4*)(out + o) = ov;
  }
};

// ---------------------------------------------------------------------------
// attention: ONE WAVE per (bh, 16-row tile). Grid 15600 x 64 thr, with
// XCD-colocating bijective remap (15600 = 8*1950). Swapped QK^T (register P);
// swapped PV; O quad<->nt transposed in-register -> one dwordx4 store/lane
// into head-major attno [bh][tok][64].
// __launch_bounds__(64): NO min-waves clamp -> allocator takes ~150 VGPR,
// zero scratch spill (the (64,4) clamp pinned 64 VGPR and spilled ~110MB).
// ---------------------------------------------------------------------------
__global__ __launch_bounds__(64) void k_attn(const i8* __restrict__ qq, const i8* __restrict__ kq,
    const i8* __restrict__ vt, const short* __restrict__ TB,
    const float* __restrict__ as, i8* __restrict__ outq) {
  __shared__ float relS[16][66];                  // rel bias [q-row][d(h)|32+d(w)]
  const int g = blockIdx.x;
  const int work = (g & 7) * 1950 + (g >> 3);    // bijective: 15600 = 8*1950
  const int bh = work / 13;
  const int t = work - bh * 13;
  const int lane = threadIdx.x;
  const int quad = lane >> 4, lc = lane & 15;
  const float s0 = as[0];
  const float ssc = s0 * as[1] * 0.125f;
  const float invs3 = 1.0f / as[3];
  const float oscale = as[2] * as[3] / as[5];

  const v8s* TBv = (const v8s*)TB;
  const v4i vz = {0, 0, 0, 0};

  // ---- rel-pos bias via bf16 MFMA (writes relS[row=quad*4+r][...]) ----
  {
    int arow = t * 16 + lc; if (arow > 195) arow = 195;
    const i8* qrow = qq + ((size_t)bh * 196 + arow) * 64;
    v8s af[2];
#pragma unroll
    for (int ks = 0; ks < 2; ks++) {
      const i8* p = qrow + ks * 32 + quad * 8;
#pragma unroll
      for (int j = 0; j < 8; j++)
        af[ks][j] = (short)(__float_as_uint((float)p[j]) >> 16);  // exact int->bf16
    }
    v4f rh0 = {0,0,0,0}, rh1 = {0,0,0,0}, rw0 = {0,0,0,0}, rw1 = {0,0,0,0};
#pragma unroll
    for (int ks = 0; ks < 2; ks++)
#pragma unroll
      for (int p2 = 0; p2 < 2; p2++) {
        rh0 = __builtin_amdgcn_mfma_f32_16x16x32_bf16(af[ks], TBv[(0*4 + ks*2 + p2)*64 + lane], rh0, 0, 0, 0);
        rh1 = __builtin_amdgcn_mfma_f32_16x16x32_bf16(af[ks], TBv[(1*4 + ks*2 + p2)*64 + lane], rh1, 0, 0, 0);
        rw0 = __builtin_amdgcn_mfma_f32_16x16x32_bf16(af[ks], TBv[(2*4 + ks*2 + p2)*64 + lane], rw0, 0, 0, 0);
        rw1 = __builtin_amdgcn_mfma_f32_16x16x32_bf16(af[ks], TBv[(3*4 + ks*2 + p2)*64 + lane], rw1, 0, 0, 0);
      }
#pragma unroll
    for (int r = 0; r < 4; r++) {
      int rl = quad * 4 + r;
      relS[rl][lc]      = rh0[r] * s0;
      relS[rl][16 + lc] = rh1[r] * s0;
      relS[rl][32 + lc] = rw0[r] * s0;
      relS[rl][48 + lc] = rw1[r] * s0;
    }
  }

  // ---- QK^T, SWAPPED (int-exact): lane (quad,lc) holds P-row q=lc at
  // k = f*16+quad*4+r ----
  v4i aq = *(const v4i*)(qq + ((size_t)bh * 196 + t * 16 + lc) * 64 + quad * 16);
  v4i sacc[13];
#pragma unroll
  for (int f = 0; f < 13; f++) {
    v4i bk = *(const v4i*)(kq + ((size_t)bh * 196 + f * 16 + lc) * 64 + quad * 16);
    sacc[f] = __builtin_amdgcn_mfma_i32_16x16x64_i8(bk, aq, vz, 0, 0, 0);
  }

  // per-reg (kh<<4|kw) nibble table: compile-time constants selected by quad
  unsigned khw[13];
#pragma unroll
  for (int f = 0; f < 13; f++) {
    unsigned w0 = 0, w1 = 0, w2 = 0, w3 = 0;
#pragma unroll
    for (int r = 0; r < 4; r++) {
      int k0 = f*16 + 0*4 + r; if (k0 > 195) k0 = 195;
      int k1 = f*16 + 1*4 + r; if (k1 > 195) k1 = 195;
      int k2 = f*16 + 2*4 + r; if (k2 > 195) k2 = 195;
      int k3 = f*16 + 3*4 + r; if (k3 > 195) k3 = 195;
      w0 |= (unsigned)(((k0/14) << 4) | (k0 - (k0/14)*14)) << (r*8);
      w1 |= (unsigned)(((k1/14) << 4) | (k1 - (k1/14)*14)) << (r*8);
      w2 |= (unsigned)(((k2/14) << 4) | (k2 - (k2/14)*14)) << (r*8);
      w3 |= (unsigned)(((k3/14) << 4) | (k3 - (k3/14)*14)) << (r*8);
    }
    khw[f] = quad == 0 ? w0 : quad == 1 ? w1 : quad == 2 ? w2 : w3;
  }

  // ---- softmax (per-lane row q = lc) ----
  int qrow = t * 16 + lc;                       // >=196 only for t=12: junk, store-guarded
  int qh = qrow / 14, qw = qrow - qh * 14;
  const float* rH = &relS[lc][13 + qh];         // rH[-kh]
  const float* rW = &relS[lc][32 + 13 + qw];    // rW[-kw]
  float L[13][4];
  float mx = -1e30f;
#pragma unroll
  for (int f = 0; f < 13; f++)
#pragma unroll
    for (int r = 0; r < 4; r++) {
      int kh = (int)((khw[f] >> (r * 8 + 4)) & 0xfu);
      int kw = (int)((khw[f] >> (r * 8)) & 0xfu);
      float v = ((f < 12) | (quad == 0))
                  ? fmaf((float)sacc[f][r], ssc, rH[-kh] + rW[-kw]) : -1e30f;
      L[f][r] = v;
      mx = fmaxf(mx, v);
    }
  mx = fmaxf(mx, __shfl_xor(mx, 16));
  mx = fmaxf(mx, __shfl_xor(mx, 32));
  float sum = 0.f;
#pragma unroll
  for (int f = 0; f < 13; f++)
#pragma unroll
    for (int r = 0; r < 4; r++) { float e = __expf(L[f][r] - mx); L[f][r] = e; sum += e; }
  sum += __shfl_xor(sum, 16);
  sum += __shfl_xor(sum, 32);
  float cq = (1.0f / sum) * invs3;

  // quantize P to packed words: W[f] = P[q=lc][f*16+quad*4 .. +4]
  unsigned W[16];
#pragma unroll
  for (int f = 0; f < 13; f++) {
    i8 q4[4];
#pragma unroll
    for (int r = 0; r < 4; r++) q4[r] = satq(L[f][r] * cq);
    W[f] = (unsigned)pack4(q4);
  }
  W[13] = 0; W[14] = 0; W[15] = 0;

  const bool q0m = (quad & 1) == 0, q1m = (quad & 2) == 0;

  // ---- PV (int-exact), A-frags via in-register 4x4 quad-word transpose ----
  v4i oacc[4];
#pragma unroll
  for (int nt = 0; nt < 4; nt++) oacc[nt] = vz;
#pragma unroll
  for (int kc = 0; kc < 4; kc++) {
    unsigned a0 = W[kc*4+0], a1 = W[kc*4+1], a2 = W[kc*4+2], a3 = W[kc*4+3];
    unsigned s0_ = (unsigned)__shfl_xor((int)a1, 16);
    unsigned s1_ = (unsigned)__shfl_xor((int)a0, 16);
    unsigned s2_ = (unsigned)__shfl_xor((int)a3, 16);
    unsigned s3_ = (unsigned)__shfl_xor((int)a2, 16);
    unsigned x0 = q0m ? a0 : s0_;
    unsigned x1 = q0m ? s1_ : a1;
    unsigned x2 = q0m ? a2 : s2_;
    unsigned x3 = q0m ? s3_ : a3;
    unsigned u0 = (unsigned)__shfl_xor((int)x2, 32);
    unsigned u1 = (unsigned)__shfl_xor((int)x3, 32);
    unsigned u2 = (unsigned)__shfl_xor((int)x0, 32);
    unsigned u3 = (unsigned)__shfl_xor((int)x1, 32);
    v4i ap;
    ap[0] = (int)(q1m ? x0 : u0);
    ap[1] = (int)(q1m ? x1 : u1);
    ap[2] = (int)(q1m ? u2 : x2);
    ap[3] = (int)(q1m ? u3 : x3);
#pragma unroll
    for (int nt = 0; nt < 4; nt++) {
      v4i bv = *(const v4i*)(vt + ((size_t)bh * 64 + nt * 16 + lc) * 256 + kc * 64 + quad * 16);
      // SWAPPED: lane holds O[q=lc][ch=nt*16+quad*4+r]
      oacc[nt] = __builtin_amdgcn_mfma_i32_16x16x64_i8(bv, ap, oacc[nt], 0, 0, 0);
    }
  }

  // quantize O to words: W2[nt] = O[q=lc] dwords (ch/4 = nt*4+quad)
  unsigned W2[4];
#pragma unroll
  for (int nt = 0; nt < 4; nt++) {
    i8 q4[4];
#pragma unroll
    for (int r = 0; r < 4; r++) q4[r] = satq((float)oacc[nt][r] * oscale);
    W2[nt] = (unsigned)pack4(q4);
  }
  // transpose quad<->nt (same butterfly) -> lane holds dwords quad*4..+3 of
  // its row -> ONE dwordx4 store.
  {
    unsigned a0 = W2[0], a1 = W2[1], a2 = W2[2], a3 = W2[3];
    unsigned s0_ = (unsigned)__shfl_xor((int)a1, 16);
    unsigned s1_ = (unsigned)__shfl_xor((int)a0, 16);
    unsigned s2_ = (unsigned)__shfl_xor((int)a3, 16);
    unsigned s3_ = (unsigned)__shfl_xor((int)a2, 16);
    unsigned x0 = q0m ? a0 : s0_;
    unsigned x1 = q0m ? s1_ : a1;
    unsigned x2 = q0m ? a2 : s2_;
    unsigned x3 = q0m ? s3_ : a3;
    unsigned u0 = (unsigned)__shfl_xor((int)x2, 32);
    unsigned u1 = (unsigned)__shfl_xor((int)x3, 32);
    unsigned u2 = (unsigned)__shfl_xor((int)x0, 32);
    unsigned u3 = (unsigned)__shfl_xor((int)x1, 32);
    v4i ot;
    ot[0] = (int)(q1m ? x0 : u0);
    ot[1] = (int)(q1m ? x1 : u1);
    ot[2] = (int)(q1m ? u2 : x2);
    ot[3] = (int)(q1m ? u3 : x3);
    if (t * 16 + lc < 196)
      *(v4i*)(outq + ((size_t)bh * 196 + t * 16 + lc) * 64 + quad * 16) = ot;
  }
}

// ---------------------------------------------------------------------------
extern "C" void kernel_launch(void* const* d_in, const int* in_sizes, int n_in,
                              void* d_out, int out_size, void* d_ws, size_t ws_size,
                              hipStream_t stream) {
  const float* x     = (const float*)d_in[0];
  const float* ln1w  = (const float*)d_in[1];
  const float* ln1b  = (const float*)d_in[2];
  const float* ln2w  = (const float*)d_in[3];
  const float* ln2b  = (const float*)d_in[4];
  const float* qkvw  = (const float*)d_in[5];
  const float* qkvb  = (const float*)d_in[6];
  const float* projw = (const float*)d_in[7];
  const float* projb = (const float*)d_in[8];
  const float* lin1w = (const float*)d_in[9];
  const float* lin1b = (const float*)d_in[10];
  const float* lin2w = (const float*)d_in[11];
  const float* lin2b = (const float*)d_in[12];
  const float* rph   = (const float*)d_in[13];
  const float* rpw   = (const float*)d_in[14];
  const float* as    = (const float*)d_in[15];
  const float* wsc   = (const float*)d_in[16];
  float* out = (float*)d_out;

  // ws layout (72,462,336 B total), regions reused across stages:
  char* ws = (char*)d_ws;
  i8* big    = (i8*)ws;                          // 50,331,648
  i8* qq     = big;                              // 15,052,800 (1200*196*64)
  i8* kq     = big + 15052800;                   // 15,052,800
  i8* vt     = big + 30105600;                   // 19,660,800 (1200*64*256)
  short* TB  = (short*)(big + 49766400);         //     16,384 (rel tables; dead before lin1)
  i8* mlpq   = big;                              // 50,331,648 (16384*3072), after attn
  i8* creg   = (i8*)(ws + 50331648);             // 15,052,800
  i8* winq   = creg;                             // qkv input
  i8* attno  = creg;                             // proj input, head-major [bh][tok][64]
  i8* yq     = creg;                             // lin1 input (after proj dead)
  i8* wqb    = (i8*)(ws + 65384448);             //  7,077,888 (all 4 wq, contiguous)
  i8* qkvwq  = wqb;
  i8* projwq = wqb + 1769472;
  i8* lin1wq = projwq + 589824;
  i8* lin2wq = lin1wq + 2359296;

  k_prep<<<1732, 256, 0, stream>>>(qkvw, projw, lin1w, lin2w, wqb, rph, rpw, TB, wsc);

  k_ln1<<<4900, 256, 0, stream>>>(x, ln1w, ln1b, as, winq);

  { EpiQKV e{as, wsc, qkvb, qq, kq, vt};
    k_gemm<EpiQKV><<<dim3(18, 154), 256, 0, stream>>>(winq, qkvwq, 19600, 2304, 768, e); }

  k_attn<<<15600, 64, 0, stream>>>(qq, kq, vt, TB, as, attno);

  { EpiProj e{as, wsc, projb, x, out};
    k_gemm<EpiProj, true><<<dim3(6, 154), 256, 0, stream>>>(attno, projwq, 19600, 768, 768, e); }

  k_ln2<<<4096, 256, 0, stream>>>(out, ln2w, ln2b, as, yq);

  { EpiLin1 e{as, wsc, lin1b, mlpq};
    k_gemm<EpiLin1><<<dim3(24, 128), 256, 0, stream>>>(yq, lin1wq, 16384, 3072, 768, e); }

  { EpiLin2 e{as, wsc, lin2b, out};
    k_gemm<EpiLin2><<<dim3(6, 128), 256, 0, stream>>>(mlpq, lin2wq, 16384, 768, 3072, e); }
}